// Round 1
// baseline (3009.932 us; speedup 1.0000x reference)
//
#include <hip/hip_runtime.h>
#include <cstdint>
#include <cstddef>

// Problem constants (fixed by the reference)
#define NB 4
#define NS 1024
#define ND 1024
#define NH 16
#define NDH 64
#define NP 112
#define NTOPK 64

__device__ __forceinline__ float dot4(float4 a, float4 b) {
  return (a.x * b.x + a.y * b.y) + (a.z * b.z + a.w * b.w);
}

// ---------------------------------------------------------------------------
// prep: L[p][e] = sum_d mu[p][d] * prec[p][d][e]  (fp64 accum)
//       c[p]    = sum_e L[p][e] * mu[p][e]
//       sw[p]   = sqrt(splat_w[p])
// ---------------------------------------------------------------------------
__global__ __launch_bounds__(64) void prep_kernel(
    const float* __restrict__ mu, const float* __restrict__ prec,
    const float* __restrict__ spw, float* __restrict__ Lg,
    float* __restrict__ cg, float* __restrict__ swg) {
  __shared__ double tmp[64];
  const int p = blockIdx.x, e = threadIdx.x;
  double acc = 0.0;
  for (int d = 0; d < 64; ++d)
    acc += (double)mu[p * 64 + d] * (double)prec[((size_t)p * 64 + d) * 64 + e];
  Lg[p * 64 + e] = (float)acc;
  tmp[e] = acc * (double)mu[p * 64 + e];
  __syncthreads();
  if (e == 0) {
    double s = 0.0;
    for (int k = 0; k < 64; ++k) s += tmp[k];
    cg[p] = (float)s;
    swg[p] = sqrtf(spw[p]);
  }
}

// ---------------------------------------------------------------------------
// gemm64: C[m,n] = X[m,:K] @ W[:K,n] + bias[n];  M=4096, N=1024, K=1024
// MODE 0: Q layout [(b*H+h)*S+s][d], scaled by Dh^-0.5 = 0.125
// MODE 1: V transposed layout [(b*H+h)*64+d][s]
// MODE 2: plain row-major [m][n] (output projection)
// ---------------------------------------------------------------------------
template <int MODE>
__global__ __launch_bounds__(256) void gemm64(
    const float* __restrict__ X, const float* __restrict__ W,
    const float* __restrict__ bias, float* __restrict__ dst) {
  __shared__ __align__(16) float As[16][64];  // [k][m]
  __shared__ __align__(16) float Bs[16][64];  // [k][n]
  const int tid = threadIdx.x;
  const int n0 = blockIdx.x * 64;
  const int m0 = blockIdx.y * 64;
  const int row0 = (tid >> 4) << 2;
  const int col0 = (tid & 15) << 2;
  const int lr = tid >> 2, lc4 = (tid & 3) << 2;
  const int wr = tid >> 4, wc4 = (tid & 15) << 2;

  float acc[4][4];
#pragma unroll
  for (int i = 0; i < 4; ++i)
#pragma unroll
    for (int j = 0; j < 4; ++j) acc[i][j] = 0.f;

  for (int k0 = 0; k0 < 1024; k0 += 16) {
    const float4 xa = *(const float4*)(X + (size_t)(m0 + lr) * 1024 + k0 + lc4);
    const float4 wb = *(const float4*)(W + (size_t)(k0 + wr) * 1024 + n0 + wc4);
    __syncthreads();  // previous tile fully consumed
    As[lc4 + 0][lr] = xa.x; As[lc4 + 1][lr] = xa.y;
    As[lc4 + 2][lr] = xa.z; As[lc4 + 3][lr] = xa.w;
    *(float4*)&Bs[wr][wc4] = wb;
    __syncthreads();
#pragma unroll
    for (int kk = 0; kk < 16; ++kk) {
      const float4 a = *(const float4*)&As[kk][row0];
      const float4 b = *(const float4*)&Bs[kk][col0];
      acc[0][0] += a.x * b.x; acc[0][1] += a.x * b.y; acc[0][2] += a.x * b.z; acc[0][3] += a.x * b.w;
      acc[1][0] += a.y * b.x; acc[1][1] += a.y * b.y; acc[1][2] += a.y * b.z; acc[1][3] += a.y * b.w;
      acc[2][0] += a.z * b.x; acc[2][1] += a.z * b.y; acc[2][2] += a.z * b.z; acc[2][3] += a.z * b.w;
      acc[3][0] += a.w * b.x; acc[3][1] += a.w * b.y; acc[3][2] += a.w * b.z; acc[3][3] += a.w * b.w;
    }
  }

  const int token0 = m0 + row0;
  const int bidx = token0 >> 10;
  const float4 bv = *(const float4*)(bias + n0 + col0);

  if (MODE == 0) {
    const int h = n0 >> 6;  // n0 is a multiple of 64
#pragma unroll
    for (int i = 0; i < 4; ++i) {
      const int s = (token0 & 1023) + i;
      float4 o;
      o.x = (acc[i][0] + bv.x) * 0.125f;
      o.y = (acc[i][1] + bv.y) * 0.125f;
      o.z = (acc[i][2] + bv.z) * 0.125f;
      o.w = (acc[i][3] + bv.w) * 0.125f;
      *(float4*)(dst + ((((size_t)bidx * NH + h) * NS + s) << 6) + col0) = o;
    }
  } else if (MODE == 1) {
    const int h = n0 >> 6;
    const int srow = token0 & 1023;
#pragma unroll
    for (int j = 0; j < 4; ++j) {
      const float bj = (j == 0) ? bv.x : (j == 1) ? bv.y : (j == 2) ? bv.z : bv.w;
      float4 o = make_float4(acc[0][j] + bj, acc[1][j] + bj, acc[2][j] + bj, acc[3][j] + bj);
      *(float4*)(dst + ((((size_t)bidx * NH + h) * 64 + (col0 + j)) << 10) + srow) = o;
    }
  } else {
#pragma unroll
    for (int i = 0; i < 4; ++i) {
      float4 o = make_float4(acc[i][0] + bv.x, acc[i][1] + bv.y,
                             acc[i][2] + bv.z, acc[i][3] + bv.w);
      *(float4*)(dst + (size_t)(token0 + i) * 1024 + n0 + col0) = o;
    }
  }
}

// ---------------------------------------------------------------------------
// phi: for each token t and splat p:
//   m = q^T P_p q - 2 L_p.q + c_p ;  Ut[bh][p][s] = sw_p * exp(-0.5 m)
// One thread per token; 28 splats per block (blockIdx.y selects chunk);
// P_p staged in LDS and read as wave-uniform broadcasts; q in 16 float4 regs.
// d4 outer loop stays a runtime loop: q[d4] fetched via a scalar-branch switch
// (uniform d4 -> s_cbranch, no divergence, no scratch).
// ---------------------------------------------------------------------------
__global__ __launch_bounds__(256) void phi_kernel(
    const float* __restrict__ Q, const float* __restrict__ prec,
    const float* __restrict__ Lg, const float* __restrict__ cg,
    const float* __restrict__ swg, float* __restrict__ Ut) {
  __shared__ float4 Ps4[64 * 16];   // P_p : [d][e4]  (16 KB)
  __shared__ float4 Ls4[28 * 16];   // L for the 28 splats of this chunk
  __shared__ float cs[28], sws[28];
  const int tid = threadIdx.x;
  const int token = blockIdx.x * 256 + tid;
  const int pbase = blockIdx.y * 28;

  for (int idx = tid; idx < 28 * 16; idx += 256)
    Ls4[idx] = ((const float4*)Lg)[(size_t)pbase * 16 + idx];
  if (tid < 28) { cs[tid] = cg[pbase + tid]; sws[tid] = swg[pbase + tid]; }

  float4 qr[16];
#pragma unroll
  for (int e4 = 0; e4 < 16; ++e4)
    qr[e4] = *(const float4*)(Q + (size_t)token * 64 + e4 * 4);

  const int bh = token >> 10;
  const int s = token & 1023;
  float* uout = Ut + (size_t)bh * NP * NS + s;

  for (int pi = 0; pi < 28; ++pi) {
    const int p = pbase + pi;
    __syncthreads();  // previous P tile fully consumed (also orders Ls4/cs)
#pragma unroll
    for (int t = 0; t < 4; ++t)
      Ps4[t * 256 + tid] = ((const float4*)prec)[(size_t)p * 1024 + t * 256 + tid];
    __syncthreads();

    float lq0 = 0.f, lq1 = 0.f;
#pragma unroll
    for (int e4 = 0; e4 < 16; e4 += 2) {
      lq0 += dot4(Ls4[pi * 16 + e4], qr[e4]);
      lq1 += dot4(Ls4[pi * 16 + e4 + 1], qr[e4 + 1]);
    }
    const float lq = lq0 + lq1;

    float m = 0.f;
#pragma unroll 1
    for (int d4 = 0; d4 < 16; ++d4) {
      float4 qd;
      switch (d4) {
        case 0:  qd = qr[0];  break; case 1:  qd = qr[1];  break;
        case 2:  qd = qr[2];  break; case 3:  qd = qr[3];  break;
        case 4:  qd = qr[4];  break; case 5:  qd = qr[5];  break;
        case 6:  qd = qr[6];  break; case 7:  qd = qr[7];  break;
        case 8:  qd = qr[8];  break; case 9:  qd = qr[9];  break;
        case 10: qd = qr[10]; break; case 11: qd = qr[11]; break;
        case 12: qd = qr[12]; break; case 13: qd = qr[13]; break;
        case 14: qd = qr[14]; break; default: qd = qr[15]; break;
      }
      float y0 = 0.f, y1 = 0.f, y2 = 0.f, y3 = 0.f;
#pragma unroll
      for (int e4 = 0; e4 < 16; ++e4) {
        const float4 qe = qr[e4];
        y0 += dot4(Ps4[(d4 * 4 + 0) * 16 + e4], qe);
        y1 += dot4(Ps4[(d4 * 4 + 1) * 16 + e4], qe);
        y2 += dot4(Ps4[(d4 * 4 + 2) * 16 + e4], qe);
        y3 += dot4(Ps4[(d4 * 4 + 3) * 16 + e4], qe);
      }
      m += (qd.x * y0 + qd.y * y1) + (qd.z * y2 + qd.w * y3);
    }
    const float mm = m - 2.f * lq + cs[pi];
    uout[(size_t)p * NS] = sws[pi] * expf(-0.5f * mm);
  }
}

// ---------------------------------------------------------------------------
// attn: per (bh, 16-row tile):
//   A[16][1024] = Ui(16xP) @ Uj(Px1024)  (Gram),  exact top-64 threshold per
//   row (bitwise binary search, >= keeps duplicates), mask columns, normalize
//   by max(rowsum,1e-12), ctx[16][64] = A @ V.
// ---------------------------------------------------------------------------
__global__ __launch_bounds__(512) void attn_kernel(
    const float* __restrict__ Ut, const float* __restrict__ Vt,
    const float* __restrict__ amask, float* __restrict__ ctx) {
  __shared__ float4 At4[16 * 256];   // 64 KB: A tile [16][1024]
  __shared__ float4 Uit4[NP * 4];    // 7 KB: Ui fragments [p][16]
  __shared__ float thrI[16], invI[16];
  float* Uit = (float*)Uit4;
  const int tid = threadIdx.x;
  const int i0 = blockIdx.x * 16;
  const int bh = blockIdx.y;
  const int bidx = bh >> 4;
  const int h = bh & 15;
  const float* Ubh = Ut + (size_t)bh * NP * NS;

  for (int idx = tid; idx < NP * 16; idx += 512) {
    const int p = idx >> 4, r = idx & 15;
    Uit[idx] = Ubh[(size_t)p * NS + i0 + r];
  }
  __syncthreads();

  // ---- Gram phase: 512 threads = 4 rowgroups x 128 colgroups, 4x8 micro ----
  {
    const int cg = tid & 127;
    const int rg = tid >> 7;
    const float* ujb = Ubh + cg * 8;
    float acc[4][8];
#pragma unroll
    for (int r = 0; r < 4; ++r)
#pragma unroll
      for (int c = 0; c < 8; ++c) acc[r][c] = 0.f;
#pragma unroll 2
    for (int p = 0; p < NP; ++p) {
      const float4 uj0 = *(const float4*)(ujb + (size_t)p * NS);
      const float4 uj1 = *(const float4*)(ujb + (size_t)p * NS + 4);
      const float4 ui = Uit4[p * 4 + rg];
#define CROW(r, uir)                                                         \
  acc[r][0] += uir * uj0.x; acc[r][1] += uir * uj0.y;                        \
  acc[r][2] += uir * uj0.z; acc[r][3] += uir * uj0.w;                        \
  acc[r][4] += uir * uj1.x; acc[r][5] += uir * uj1.y;                        \
  acc[r][6] += uir * uj1.z; acc[r][7] += uir * uj1.w;
      CROW(0, ui.x) CROW(1, ui.y) CROW(2, ui.z) CROW(3, ui.w)
#undef CROW
    }
#pragma unroll
    for (int r = 0; r < 4; ++r) {
      At4[((rg * 4 + r) << 8) + cg * 2] =
          make_float4(acc[r][0], acc[r][1], acc[r][2], acc[r][3]);
      At4[((rg * 4 + r) << 8) + cg * 2 + 1] =
          make_float4(acc[r][4], acc[r][5], acc[r][6], acc[r][7]);
    }
  }
  __syncthreads();

  // ---- exact top-64 threshold per row + denominator ----
  {
    const int wave = tid >> 6, lane = tid & 63;
#pragma unroll 1
    for (int rr = 0; rr < 2; ++rr) {
      const int r = wave * 2 + rr;
      float fv[16];
#pragma unroll
      for (int k4 = 0; k4 < 4; ++k4) {
        const float4 v = At4[(r << 8) + lane * 4 + k4];
        fv[k4 * 4 + 0] = v.x; fv[k4 * 4 + 1] = v.y;
        fv[k4 * 4 + 2] = v.z; fv[k4 * 4 + 3] = v.w;
      }
      // all values >= 0 -> uint order == float order; greedy bit search for
      // the largest c with count(v >= c) >= 64  ==  exact 64th-largest value
      unsigned c = 0u;
      for (int bit = 30; bit >= 0; --bit) {
        const unsigned cand = c | (1u << bit);
        int cnt = 0;
#pragma unroll
        for (int k = 0; k < 16; ++k)
          cnt += (int)__popcll(__ballot(__float_as_uint(fv[k]) >= cand));
        if (cnt >= NTOPK) c = cand;
      }
      const float thr = __uint_as_float(c);
      float ssum = 0.f;
      const float4* mrow4 = (const float4*)(amask + (bidx << 10) + (lane << 4));
#pragma unroll
      for (int k4 = 0; k4 < 4; ++k4) {
        const float4 mk = mrow4[k4];
        ssum += (fv[k4 * 4 + 0] >= thr ? fv[k4 * 4 + 0] : 0.f) * mk.x;
        ssum += (fv[k4 * 4 + 1] >= thr ? fv[k4 * 4 + 1] : 0.f) * mk.y;
        ssum += (fv[k4 * 4 + 2] >= thr ? fv[k4 * 4 + 2] : 0.f) * mk.z;
        ssum += (fv[k4 * 4 + 3] >= thr ? fv[k4 * 4 + 3] : 0.f) * mk.w;
      }
#pragma unroll
      for (int off = 32; off > 0; off >>= 1) ssum += __shfl_xor(ssum, off, 64);
      if (lane == 0) {
        thrI[r] = thr;
        invI[r] = 1.0f / fmaxf(ssum, 1e-12f);
      }
    }
  }
  __syncthreads();

  // ---- normalize in place: a = (a>=thr) ? a*mask*inv : 0 ----
  {
    const float4* m4 = (const float4*)(amask + (bidx << 10));
    for (int idx = tid; idx < 16 * 256; idx += 512) {
      const int r = idx >> 8;
      const int j4 = idx & 255;
      float4 a = At4[idx];
      const float4 mv = m4[j4];
      const float thr = thrI[r], inv = invI[r];
      a.x = (a.x >= thr) ? a.x * mv.x * inv : 0.f;
      a.y = (a.y >= thr) ? a.y * mv.y * inv : 0.f;
      a.z = (a.z >= thr) ? a.z * mv.z * inv : 0.f;
      a.w = (a.w >= thr) ? a.w * mv.w * inv : 0.f;
      At4[idx] = a;
    }
  }
  __syncthreads();

  // ---- ctx = A @ V : thread = (output col, row pair) ----
  {
    const int ccol = tid & 63;
    const int crg = tid >> 6;  // 0..7 -> rows crg*2, crg*2+1
    const float* vrow = Vt + ((size_t)bh * 64 + ccol) * NS;
    const float4* a0p = At4 + ((crg * 2 + 0) << 8);
    const float4* a1p = At4 + ((crg * 2 + 1) << 8);
    float s0 = 0.f, s1 = 0.f;
#pragma unroll 4
    for (int j4 = 0; j4 < 256; ++j4) {
      const float4 vv = *(const float4*)(vrow + (j4 << 2));
      s0 += dot4(a0p[j4], vv);
      s1 += dot4(a1p[j4], vv);
    }
    const int row = (bidx << 10) + i0 + crg * 2;
    ctx[(size_t)row * 1024 + (h << 6) + ccol] = s0;
    ctx[(size_t)(row + 1) * 1024 + (h << 6) + ccol] = s1;
  }
}

// ---------------------------------------------------------------------------
extern "C" void kernel_launch(void* const* d_in, const int* in_sizes, int n_in,
                              void* d_out, int out_size, void* d_ws,
                              size_t ws_size, hipStream_t stream) {
  (void)in_sizes; (void)n_in; (void)out_size; (void)ws_size;
  const float* hs    = (const float*)d_in[0];
  const float* amask = (const float*)d_in[1];
  const float* Wq    = (const float*)d_in[2];
  const float* bq    = (const float*)d_in[3];
  // d_in[4], d_in[5] = Wk, bk : projected-but-unused in the reference
  const float* Wv    = (const float*)d_in[6];
  const float* bv    = (const float*)d_in[7];
  const float* Wo    = (const float*)d_in[8];
  const float* bo    = (const float*)d_in[9];
  const float* mu    = (const float*)d_in[10];
  const float* prec  = (const float*)d_in[11];
  const float* spw   = (const float*)d_in[12];
  float* out = (float*)d_out;

  float* w   = (float*)d_ws;
  float* Q   = w;                 // 4,194,304 floats [(b h s)][64]
  float* Vt  = w + 4194304;       // 4,194,304 floats [(b h d)][s]
  float* Ut  = w + 8388608;       // 7,340,032 floats [(b h p)][s]
  float* Lg  = w + 15728640;      // 7168
  float* cg  = w + 15735808;      // 112
  float* swg = w + 15735920;      // 112
  float* ctxb = w;                // reuse Q region (Q dead after phi_kernel)

  prep_kernel<<<dim3(NP), dim3(64), 0, stream>>>(mu, prec, spw, Lg, cg, swg);
  gemm64<0><<<dim3(16, 64), dim3(256), 0, stream>>>(hs, Wq, bq, Q);
  gemm64<1><<<dim3(16, 64), dim3(256), 0, stream>>>(hs, Wv, bv, Vt);
  phi_kernel<<<dim3(256, 4), dim3(256), 0, stream>>>(Q, prec, Lg, cg, swg, Ut);
  attn_kernel<<<dim3(64, 64), dim3(512), 0, stream>>>(Ut, Vt, amask, ctxb);
  gemm64<2><<<dim3(16, 64), dim3(256), 0, stream>>>(ctxb, Wo, bo, out);
}

// Round 2
// 2075.004 us; speedup vs baseline: 1.4506x; 1.4506x over previous
//
#include <hip/hip_runtime.h>
#include <cstdint>
#include <cstddef>

// Problem constants (fixed by the reference)
#define NB 4
#define NS 1024
#define ND 1024
#define NH 16
#define NDH 64
#define NP 112
#define NTOPK 64
#define PHI_CH 14  // splats per phi chunk (8 chunks)

__device__ __forceinline__ float dot4(float4 a, float4 b) {
  return (a.x * b.x + a.y * b.y) + (a.z * b.z + a.w * b.w);
}

// ---------------------------------------------------------------------------
// prep: per splat, fp64 Cholesky P = L L^T (right-looking, 64 threads).
// Writes Rf[p][d][e] = L[e][d] for e>=d else 0  (so m = || Rf q - Rf mu ||^2),
// tneg[p][d] = -(Rf mu)_d, swg[p] = sqrt(splat_w[p]).
// ---------------------------------------------------------------------------
__global__ __launch_bounds__(64) void prep_kernel(
    const float* __restrict__ mu, const float* __restrict__ prec,
    const float* __restrict__ spw, float* __restrict__ Rf,
    float* __restrict__ tneg, float* __restrict__ swg) {
  __shared__ double A[64][64];  // 32 KB
  const int p = blockIdx.x, t = threadIdx.x;
  for (int e = 0; e < 64; ++e)
    A[t][e] = (double)prec[((size_t)p * 64 + t) * 64 + e];
  __syncthreads();
  for (int k = 0; k < 64; ++k) {
    if (t == k) A[k][k] = sqrt(A[k][k]);
    __syncthreads();
    if (t > k) A[t][k] /= A[k][k];
    __syncthreads();
    if (t > k) {
      const double lik = A[t][k];
      for (int j = k + 1; j <= t; ++j) A[t][j] -= lik * A[j][k];
    }
    __syncthreads();
  }
  // row t of Rf: Rf[t][e] = L[e][t] (e>=t), zeros below
  float* rrow = Rf + ((size_t)p << 12) + t * 64;
  for (int e = 0; e < 64; ++e) rrow[e] = (e >= t) ? (float)A[e][t] : 0.f;
  double s = 0.0;
  for (int e = t; e < 64; ++e) s += A[e][t] * (double)mu[p * 64 + e];
  tneg[p * 64 + t] = (float)(-s);
  if (t == 0) swg[p] = sqrtf(spw[p]);
}

// ---------------------------------------------------------------------------
// gemm128: C[m,n] = X[m,:1024] @ W[:1024,n] + bias[n]; tile 128(M) x 64(N),
// 256 threads, micro 8x4, K-step 16.
// MODE 0: Q layout [(b*H+h)*S+s][d], scaled by 0.125
// MODE 1: V transposed layout [(b*H+h)*64+d][s]
// MODE 2: plain row-major (output projection)
// ---------------------------------------------------------------------------
template <int MODE>
__global__ __launch_bounds__(256) void gemm128(
    const float* __restrict__ X, const float* __restrict__ W,
    const float* __restrict__ bias, float* __restrict__ dst) {
  __shared__ __align__(16) float As[16][132];  // [k][m] padded
  __shared__ __align__(16) float Bs[16][68];   // [k][n] padded
  const int tid = threadIdx.x;
  const int n0 = blockIdx.x * 64;
  const int m0 = blockIdx.y * 128;
  const int tr = tid >> 4, tc = tid & 15;
  const int r0 = tr * 8, c0 = tc * 4;
  const int lm = tid >> 2, lk4 = (tid & 3) << 2;   // X staging
  const int wk = tid >> 4, wn4 = (tid & 15) << 2;  // W staging

  float acc[8][4];
#pragma unroll
  for (int i = 0; i < 8; ++i)
#pragma unroll
    for (int j = 0; j < 4; ++j) acc[i][j] = 0.f;

  for (int k0 = 0; k0 < 1024; k0 += 16) {
    const float4 xa = *(const float4*)(X + (size_t)(m0 + lm) * 1024 + k0 + lk4);
    const float4 xb = *(const float4*)(X + (size_t)(m0 + 64 + lm) * 1024 + k0 + lk4);
    const float4 wb = *(const float4*)(W + (size_t)(k0 + wk) * 1024 + n0 + wn4);
    __syncthreads();  // previous tile consumed
    As[lk4 + 0][lm] = xa.x; As[lk4 + 1][lm] = xa.y;
    As[lk4 + 2][lm] = xa.z; As[lk4 + 3][lm] = xa.w;
    As[lk4 + 0][lm + 64] = xb.x; As[lk4 + 1][lm + 64] = xb.y;
    As[lk4 + 2][lm + 64] = xb.z; As[lk4 + 3][lm + 64] = xb.w;
    *(float4*)&Bs[wk][wn4] = wb;
    __syncthreads();
#pragma unroll
    for (int kk = 0; kk < 16; ++kk) {
      const float4 a0 = *(const float4*)&As[kk][r0];
      const float4 a1 = *(const float4*)&As[kk][r0 + 4];
      const float4 b = *(const float4*)&Bs[kk][c0];
#define FMAROW(idx, av)                                                      \
  acc[idx][0] += av * b.x; acc[idx][1] += av * b.y;                          \
  acc[idx][2] += av * b.z; acc[idx][3] += av * b.w;
      FMAROW(0, a0.x) FMAROW(1, a0.y) FMAROW(2, a0.z) FMAROW(3, a0.w)
      FMAROW(4, a1.x) FMAROW(5, a1.y) FMAROW(6, a1.z) FMAROW(7, a1.w)
#undef FMAROW
    }
  }

  const float4 bv = *(const float4*)(bias + n0 + c0);
  const int token0 = m0 + r0;     // 8 consecutive tokens
  const int bidx = token0 >> 10;  // tile never straddles b (128 | 1024)
  if (MODE == 0) {
    const int h = n0 >> 6;
#pragma unroll
    for (int i = 0; i < 8; ++i) {
      const int s = (token0 & 1023) + i;
      float4 o;
      o.x = (acc[i][0] + bv.x) * 0.125f;
      o.y = (acc[i][1] + bv.y) * 0.125f;
      o.z = (acc[i][2] + bv.z) * 0.125f;
      o.w = (acc[i][3] + bv.w) * 0.125f;
      *(float4*)(dst + ((((size_t)bidx * NH + h) * NS + s) << 6) + c0) = o;
    }
  } else if (MODE == 1) {
    const int h = n0 >> 6;
    const int srow = token0 & 1023;
#pragma unroll
    for (int j = 0; j < 4; ++j) {
      const float bj = (j == 0) ? bv.x : (j == 1) ? bv.y : (j == 2) ? bv.z : bv.w;
      float* dp = dst + ((((size_t)bidx * NH + h) * 64 + (c0 + j)) << 10) + srow;
      *(float4*)dp = make_float4(acc[0][j] + bj, acc[1][j] + bj,
                                 acc[2][j] + bj, acc[3][j] + bj);
      *(float4*)(dp + 4) = make_float4(acc[4][j] + bj, acc[5][j] + bj,
                                       acc[6][j] + bj, acc[7][j] + bj);
    }
  } else {
#pragma unroll
    for (int i = 0; i < 8; ++i) {
      float4 o = make_float4(acc[i][0] + bv.x, acc[i][1] + bv.y,
                             acc[i][2] + bv.z, acc[i][3] + bv.w);
      *(float4*)(dst + (size_t)(token0 + i) * 1024 + n0 + c0) = o;
    }
  }
}

// ---------------------------------------------------------------------------
// phi: m = || R q + tneg ||^2 over the upper triangle of R; 2 tokens/thread
// (token and token+32768), fully unrolled triangle -> pure FMA chains, R
// staged in LDS (wave-uniform broadcast reads).
// Ut[bh][p][s] = sw_p * exp(-0.5 m)
// ---------------------------------------------------------------------------
__global__ __launch_bounds__(256) void phi_kernel(
    const float* __restrict__ Q, const float* __restrict__ Rf,
    const float* __restrict__ tneg, const float* __restrict__ swg,
    float* __restrict__ Ut) {
  __shared__ float4 Rs4[64 * 16];       // 16 KB: R [d][e4]
  __shared__ float4 ts4[PHI_CH * 16];   // tneg fragments [pi][d4]
  __shared__ float sws[PHI_CH];
  const int tid = threadIdx.x;
  const int token0 = blockIdx.x * 256 + tid;  // 0..32767
  const int pbase = blockIdx.y * PHI_CH;

  for (int idx = tid; idx < PHI_CH * 16; idx += 256)
    ts4[idx] = ((const float4*)tneg)[(size_t)pbase * 16 + idx];
  if (tid < PHI_CH) sws[tid] = swg[pbase + tid];

  float4 qa[16], qb[16];
#pragma unroll
  for (int e4 = 0; e4 < 16; ++e4) {
    qa[e4] = *(const float4*)(Q + ((size_t)token0 << 6) + e4 * 4);
    qb[e4] = *(const float4*)(Q + ((size_t)(token0 + 32768) << 6) + e4 * 4);
  }

  const int bh0 = token0 >> 10;
  const int s = token0 & 1023;
  float* uout0 = Ut + (size_t)bh0 * NP * NS + s;
  float* uout1 = uout0 + (size_t)32 * NP * NS;

  for (int pi = 0; pi < PHI_CH; ++pi) {
    __syncthreads();  // previous R tile consumed (also orders ts4/sws once)
    const float4* rsrc = ((const float4*)Rf) + ((size_t)(pbase + pi) << 10);
#pragma unroll
    for (int t4 = 0; t4 < 4; ++t4) Rs4[t4 * 256 + tid] = rsrc[t4 * 256 + tid];
    __syncthreads();

    float ma = 0.f, mb = 0.f;
#pragma unroll
    for (int d4 = 0; d4 < 16; ++d4) {
      const float4 tv = ts4[pi * 16 + d4];
      float ya0 = tv.x, ya1 = tv.y, ya2 = tv.z, ya3 = tv.w;
      float yb0 = tv.x, yb1 = tv.y, yb2 = tv.z, yb3 = tv.w;
#pragma unroll
      for (int e4 = d4; e4 < 16; ++e4) {
        const float4 r0 = Rs4[(d4 * 4 + 0) * 16 + e4];
        const float4 r1 = Rs4[(d4 * 4 + 1) * 16 + e4];
        const float4 r2 = Rs4[(d4 * 4 + 2) * 16 + e4];
        const float4 r3 = Rs4[(d4 * 4 + 3) * 16 + e4];
        const float4 qa_ = qa[e4];
        const float4 qb_ = qb[e4];
        ya0 += r0.x * qa_.x; ya0 += r0.y * qa_.y; ya0 += r0.z * qa_.z; ya0 += r0.w * qa_.w;
        ya1 += r1.x * qa_.x; ya1 += r1.y * qa_.y; ya1 += r1.z * qa_.z; ya1 += r1.w * qa_.w;
        ya2 += r2.x * qa_.x; ya2 += r2.y * qa_.y; ya2 += r2.z * qa_.z; ya2 += r2.w * qa_.w;
        ya3 += r3.x * qa_.x; ya3 += r3.y * qa_.y; ya3 += r3.z * qa_.z; ya3 += r3.w * qa_.w;
        yb0 += r0.x * qb_.x; yb0 += r0.y * qb_.y; yb0 += r0.z * qb_.z; yb0 += r0.w * qb_.w;
        yb1 += r1.x * qb_.x; yb1 += r1.y * qb_.y; yb1 += r1.z * qb_.z; yb1 += r1.w * qb_.w;
        yb2 += r2.x * qb_.x; yb2 += r2.y * qb_.y; yb2 += r2.z * qb_.z; yb2 += r2.w * qb_.w;
        yb3 += r3.x * qb_.x; yb3 += r3.y * qb_.y; yb3 += r3.z * qb_.z; yb3 += r3.w * qb_.w;
      }
      ma += ya0 * ya0; ma += ya1 * ya1; ma += ya2 * ya2; ma += ya3 * ya3;
      mb += yb0 * yb0; mb += yb1 * yb1; mb += yb2 * yb2; mb += yb3 * yb3;
    }
    const float sw = sws[pi];
    uout0[(size_t)(pbase + pi) << 10] = sw * expf(-0.5f * ma);
    uout1[(size_t)(pbase + pi) << 10] = sw * expf(-0.5f * mb);
  }
}

// ---------------------------------------------------------------------------
// attn: per (bh, 16-row tile): Gram A = Ui Uj^T, exact top-64 threshold per
// row (bitwise search over non-negative floats), mask, normalize, A @ V.
// ---------------------------------------------------------------------------
__global__ __launch_bounds__(512) void attn_kernel(
    const float* __restrict__ Ut, const float* __restrict__ Vt,
    const float* __restrict__ amask, float* __restrict__ ctx) {
  __shared__ float4 At4[16 * 256];   // 64 KB: A tile [16][1024]
  __shared__ float4 Uit4[NP * 4];    // 7 KB: Ui fragments [p][16]
  __shared__ float thrI[16], invI[16];
  float* Uit = (float*)Uit4;
  const int tid = threadIdx.x;
  const int i0 = blockIdx.x * 16;
  const int bh = blockIdx.y;
  const int bidx = bh >> 4;
  const int h = bh & 15;
  const float* Ubh = Ut + (size_t)bh * NP * NS;

  for (int idx = tid; idx < NP * 16; idx += 512) {
    const int p = idx >> 4, r = idx & 15;
    Uit[idx] = Ubh[(size_t)p * NS + i0 + r];
  }
  __syncthreads();

  {
    const int cg = tid & 127;
    const int rg = tid >> 7;
    const float* ujb = Ubh + cg * 8;
    float acc[4][8];
#pragma unroll
    for (int r = 0; r < 4; ++r)
#pragma unroll
      for (int c = 0; c < 8; ++c) acc[r][c] = 0.f;
#pragma unroll 2
    for (int p = 0; p < NP; ++p) {
      const float4 uj0 = *(const float4*)(ujb + (size_t)p * NS);
      const float4 uj1 = *(const float4*)(ujb + (size_t)p * NS + 4);
      const float4 ui = Uit4[p * 4 + rg];
#define CROW(r, uir)                                                         \
  acc[r][0] += uir * uj0.x; acc[r][1] += uir * uj0.y;                        \
  acc[r][2] += uir * uj0.z; acc[r][3] += uir * uj0.w;                        \
  acc[r][4] += uir * uj1.x; acc[r][5] += uir * uj1.y;                        \
  acc[r][6] += uir * uj1.z; acc[r][7] += uir * uj1.w;
      CROW(0, ui.x) CROW(1, ui.y) CROW(2, ui.z) CROW(3, ui.w)
#undef CROW
    }
#pragma unroll
    for (int r = 0; r < 4; ++r) {
      At4[((rg * 4 + r) << 8) + cg * 2] =
          make_float4(acc[r][0], acc[r][1], acc[r][2], acc[r][3]);
      At4[((rg * 4 + r) << 8) + cg * 2 + 1] =
          make_float4(acc[r][4], acc[r][5], acc[r][6], acc[r][7]);
    }
  }
  __syncthreads();

  {
    const int wave = tid >> 6, lane = tid & 63;
#pragma unroll 1
    for (int rr = 0; rr < 2; ++rr) {
      const int r = wave * 2 + rr;
      float fv[16];
#pragma unroll
      for (int k4 = 0; k4 < 4; ++k4) {
        const float4 v = At4[(r << 8) + lane * 4 + k4];
        fv[k4 * 4 + 0] = v.x; fv[k4 * 4 + 1] = v.y;
        fv[k4 * 4 + 2] = v.z; fv[k4 * 4 + 3] = v.w;
      }
      unsigned c = 0u;
      for (int bit = 30; bit >= 0; --bit) {
        const unsigned cand = c | (1u << bit);
        int cnt = 0;
#pragma unroll
        for (int k = 0; k < 16; ++k)
          cnt += (int)__popcll(__ballot(__float_as_uint(fv[k]) >= cand));
        if (cnt >= NTOPK) c = cand;
      }
      const float thr = __uint_as_float(c);
      float ssum = 0.f;
      const float4* mrow4 = (const float4*)(amask + (bidx << 10) + (lane << 4));
#pragma unroll
      for (int k4 = 0; k4 < 4; ++k4) {
        const float4 mk = mrow4[k4];
        ssum += (fv[k4 * 4 + 0] >= thr ? fv[k4 * 4 + 0] : 0.f) * mk.x;
        ssum += (fv[k4 * 4 + 1] >= thr ? fv[k4 * 4 + 1] : 0.f) * mk.y;
        ssum += (fv[k4 * 4 + 2] >= thr ? fv[k4 * 4 + 2] : 0.f) * mk.z;
        ssum += (fv[k4 * 4 + 3] >= thr ? fv[k4 * 4 + 3] : 0.f) * mk.w;
      }
#pragma unroll
      for (int off = 32; off > 0; off >>= 1) ssum += __shfl_xor(ssum, off, 64);
      if (lane == 0) {
        thrI[r] = thr;
        invI[r] = 1.0f / fmaxf(ssum, 1e-12f);
      }
    }
  }
  __syncthreads();

  {
    const float4* m4 = (const float4*)(amask + (bidx << 10));
    for (int idx = tid; idx < 16 * 256; idx += 512) {
      const int r = idx >> 8;
      const int j4 = idx & 255;
      float4 a = At4[idx];
      const float4 mv = m4[j4];
      const float thr = thrI[r], inv = invI[r];
      a.x = (a.x >= thr) ? a.x * mv.x * inv : 0.f;
      a.y = (a.y >= thr) ? a.y * mv.y * inv : 0.f;
      a.z = (a.z >= thr) ? a.z * mv.z * inv : 0.f;
      a.w = (a.w >= thr) ? a.w * mv.w * inv : 0.f;
      At4[idx] = a;
    }
  }
  __syncthreads();

  {
    const int ccol = tid & 63;
    const int crg = tid >> 6;
    const float* vrow = Vt + ((size_t)bh * 64 + ccol) * NS;
    const float4* a0p = At4 + ((crg * 2 + 0) << 8);
    const float4* a1p = At4 + ((crg * 2 + 1) << 8);
    float s0 = 0.f, s1 = 0.f;
#pragma unroll 4
    for (int j4 = 0; j4 < 256; ++j4) {
      const float4 vv = *(const float4*)(vrow + (j4 << 2));
      s0 += dot4(a0p[j4], vv);
      s1 += dot4(a1p[j4], vv);
    }
    const int row = (bidx << 10) + i0 + crg * 2;
    ctx[(size_t)row * 1024 + (h << 6) + ccol] = s0;
    ctx[(size_t)(row + 1) * 1024 + (h << 6) + ccol] = s1;
  }
}

// ---------------------------------------------------------------------------
extern "C" void kernel_launch(void* const* d_in, const int* in_sizes, int n_in,
                              void* d_out, int out_size, void* d_ws,
                              size_t ws_size, hipStream_t stream) {
  (void)in_sizes; (void)n_in; (void)out_size; (void)ws_size;
  const float* hs    = (const float*)d_in[0];
  const float* amask = (const float*)d_in[1];
  const float* Wq    = (const float*)d_in[2];
  const float* bq    = (const float*)d_in[3];
  // d_in[4], d_in[5] = Wk, bk : projected-but-unused in the reference
  const float* Wv    = (const float*)d_in[6];
  const float* bv    = (const float*)d_in[7];
  const float* Wo    = (const float*)d_in[8];
  const float* bo    = (const float*)d_in[9];
  const float* mu    = (const float*)d_in[10];
  const float* prec  = (const float*)d_in[11];
  const float* spw   = (const float*)d_in[12];
  float* out = (float*)d_out;

  float* w    = (float*)d_ws;
  float* Q    = w;                 // 4,194,304 floats [(b h s)][64]
  float* Vt   = w + 4194304;       // 4,194,304 floats [(b h d)][s] (after phi)
  float* Rf   = w + 4194304;       // 458,752 floats — alive only until phi done
  float* tneg = w + 4653056;       // 7,168
  float* swg  = w + 4660224;       // 112
  float* Ut   = w + 8388608;       // 7,340,032 floats [(b h p)][s]
  float* ctxb = w;                 // reuse Q region (Q dead after phi)

  prep_kernel<<<dim3(NP), dim3(64), 0, stream>>>(mu, prec, spw, Rf, tneg, swg);
  gemm128<0><<<dim3(16, 32), dim3(256), 0, stream>>>(hs, Wq, bq, Q);
  phi_kernel<<<dim3(128, 8), dim3(256), 0, stream>>>(Q, Rf, tneg, swg, Ut);
  gemm128<1><<<dim3(16, 32), dim3(256), 0, stream>>>(hs, Wv, bv, Vt);
  attn_kernel<<<dim3(64, 64), dim3(512), 0, stream>>>(Ut, Vt, amask, ctxb);
  gemm128<2><<<dim3(16, 32), dim3(256), 0, stream>>>(ctxb, Wo, bo, out);
}

// Round 3
// 1300.347 us; speedup vs baseline: 2.3147x; 1.5957x over previous
//
#include <hip/hip_runtime.h>
#include <cstdint>
#include <cstddef>

// Problem constants (fixed by the reference)
#define NB 4
#define NS 1024
#define ND 1024
#define NH 16
#define NDH 64
#define NP 112
#define NTOPK 64
#define PHI_CH 14  // splats per phi chunk (8 chunks)
#define NZCAP 128  // per-row compacted nonzero capacity (>=64; ties beyond cap ~impossible)

__device__ __forceinline__ float dot4(float4 a, float4 b) {
  return (a.x * b.x + a.y * b.y) + (a.z * b.z + a.w * b.w);
}

// ---------------------------------------------------------------------------
// prep: per splat, fp64 Cholesky P = L L^T (right-looking, 64 threads).
// Writes Rf[p][d][e] = L[e][d] for e>=d else 0  (so m = || Rf q - Rf mu ||^2),
// tneg[p][d] = -(Rf mu)_d, swg[p] = sqrt(splat_w[p]).
// ---------------------------------------------------------------------------
__global__ __launch_bounds__(64) void prep_kernel(
    const float* __restrict__ mu, const float* __restrict__ prec,
    const float* __restrict__ spw, float* __restrict__ Rf,
    float* __restrict__ tneg, float* __restrict__ swg) {
  __shared__ double A[64][64];  // 32 KB
  const int p = blockIdx.x, t = threadIdx.x;
  for (int e = 0; e < 64; ++e)
    A[t][e] = (double)prec[((size_t)p * 64 + t) * 64 + e];
  __syncthreads();
  for (int k = 0; k < 64; ++k) {
    if (t == k) A[k][k] = sqrt(A[k][k]);
    __syncthreads();
    if (t > k) A[t][k] /= A[k][k];
    __syncthreads();
    if (t > k) {
      const double lik = A[t][k];
      for (int j = k + 1; j <= t; ++j) A[t][j] -= lik * A[j][k];
    }
    __syncthreads();
  }
  // row t of Rf: Rf[t][e] = L[e][t] (e>=t), zeros below
  float* rrow = Rf + ((size_t)p << 12) + t * 64;
  for (int e = 0; e < 64; ++e) rrow[e] = (e >= t) ? (float)A[e][t] : 0.f;
  double s = 0.0;
  for (int e = t; e < 64; ++e) s += A[e][t] * (double)mu[p * 64 + e];
  tneg[p * 64 + t] = (float)(-s);
  if (t == 0) swg[p] = sqrtf(spw[p]);
}

// ---------------------------------------------------------------------------
// gemm128: C[m,n] = X[m,:1024] @ W[:1024,n] + bias[n]; tile 128(M) x 64(N),
// 256 threads, micro 8x4, K-step 16.
// MODE 0: head-split layout [(b*H+h)*S+s][d], scaled by 0.125 (Q)
// MODE 1: head-split layout, no scale (V)
// MODE 2: plain row-major (output projection)
// ---------------------------------------------------------------------------
template <int MODE>
__global__ __launch_bounds__(256) void gemm128(
    const float* __restrict__ X, const float* __restrict__ W,
    const float* __restrict__ bias, float* __restrict__ dst) {
  __shared__ __align__(16) float As[16][132];  // [k][m] padded
  __shared__ __align__(16) float Bs[16][68];   // [k][n] padded
  const int tid = threadIdx.x;
  const int n0 = blockIdx.x * 64;
  const int m0 = blockIdx.y * 128;
  const int tr = tid >> 4, tc = tid & 15;
  const int r0 = tr * 8, c0 = tc * 4;
  const int lm = tid >> 2, lk4 = (tid & 3) << 2;   // X staging
  const int wk = tid >> 4, wn4 = (tid & 15) << 2;  // W staging

  float acc[8][4];
#pragma unroll
  for (int i = 0; i < 8; ++i)
#pragma unroll
    for (int j = 0; j < 4; ++j) acc[i][j] = 0.f;

  for (int k0 = 0; k0 < 1024; k0 += 16) {
    const float4 xa = *(const float4*)(X + (size_t)(m0 + lm) * 1024 + k0 + lk4);
    const float4 xb = *(const float4*)(X + (size_t)(m0 + 64 + lm) * 1024 + k0 + lk4);
    const float4 wb = *(const float4*)(W + (size_t)(k0 + wk) * 1024 + n0 + wn4);
    __syncthreads();  // previous tile consumed
    As[lk4 + 0][lm] = xa.x; As[lk4 + 1][lm] = xa.y;
    As[lk4 + 2][lm] = xa.z; As[lk4 + 3][lm] = xa.w;
    As[lk4 + 0][lm + 64] = xb.x; As[lk4 + 1][lm + 64] = xb.y;
    As[lk4 + 2][lm + 64] = xb.z; As[lk4 + 3][lm + 64] = xb.w;
    *(float4*)&Bs[wk][wn4] = wb;
    __syncthreads();
#pragma unroll
    for (int kk = 0; kk < 16; ++kk) {
      const float4 a0 = *(const float4*)&As[kk][r0];
      const float4 a1 = *(const float4*)&As[kk][r0 + 4];
      const float4 b = *(const float4*)&Bs[kk][c0];
#define FMAROW(idx, av)                                                      \
  acc[idx][0] += av * b.x; acc[idx][1] += av * b.y;                          \
  acc[idx][2] += av * b.z; acc[idx][3] += av * b.w;
      FMAROW(0, a0.x) FMAROW(1, a0.y) FMAROW(2, a0.z) FMAROW(3, a0.w)
      FMAROW(4, a1.x) FMAROW(5, a1.y) FMAROW(6, a1.z) FMAROW(7, a1.w)
#undef FMAROW
    }
  }

  const float4 bv = *(const float4*)(bias + n0 + c0);
  const int token0 = m0 + r0;     // 8 consecutive tokens
  const int bidx = token0 >> 10;  // tile never straddles b (128 | 1024)
  if (MODE == 0 || MODE == 1) {
    const int h = n0 >> 6;
    const float sc = (MODE == 0) ? 0.125f : 1.0f;
#pragma unroll
    for (int i = 0; i < 8; ++i) {
      const int s = (token0 & 1023) + i;
      float4 o;
      o.x = (acc[i][0] + bv.x) * sc;
      o.y = (acc[i][1] + bv.y) * sc;
      o.z = (acc[i][2] + bv.z) * sc;
      o.w = (acc[i][3] + bv.w) * sc;
      *(float4*)(dst + ((((size_t)bidx * NH + h) * NS + s) << 6) + c0) = o;
    }
  } else {
#pragma unroll
    for (int i = 0; i < 8; ++i) {
      float4 o = make_float4(acc[i][0] + bv.x, acc[i][1] + bv.y,
                             acc[i][2] + bv.z, acc[i][3] + bv.w);
      *(float4*)(dst + (size_t)(token0 + i) * 1024 + n0 + c0) = o;
    }
  }
}

// ---------------------------------------------------------------------------
// phi: m = || R q + tneg ||^2 over the upper triangle of R; 2 tokens/thread
// (token and token+32768), fully unrolled triangle -> pure FMA chains, R
// staged in LDS (wave-uniform broadcast reads).
// Ut[bh][p][s] = sw_p * exp(-0.5 m)
// ---------------------------------------------------------------------------
__global__ __launch_bounds__(256) void phi_kernel(
    const float* __restrict__ Q, const float* __restrict__ Rf,
    const float* __restrict__ tneg, const float* __restrict__ swg,
    float* __restrict__ Ut) {
  __shared__ float4 Rs4[64 * 16];       // 16 KB: R [d][e4]
  __shared__ float4 ts4[PHI_CH * 16];   // tneg fragments [pi][d4]
  __shared__ float sws[PHI_CH];
  const int tid = threadIdx.x;
  const int token0 = blockIdx.x * 256 + tid;  // 0..32767
  const int pbase = blockIdx.y * PHI_CH;

  for (int idx = tid; idx < PHI_CH * 16; idx += 256)
    ts4[idx] = ((const float4*)tneg)[(size_t)pbase * 16 + idx];
  if (tid < PHI_CH) sws[tid] = swg[pbase + tid];

  float4 qa[16], qb[16];
#pragma unroll
  for (int e4 = 0; e4 < 16; ++e4) {
    qa[e4] = *(const float4*)(Q + ((size_t)token0 << 6) + e4 * 4);
    qb[e4] = *(const float4*)(Q + ((size_t)(token0 + 32768) << 6) + e4 * 4);
  }

  const int bh0 = token0 >> 10;
  const int s = token0 & 1023;
  float* uout0 = Ut + (size_t)bh0 * NP * NS + s;
  float* uout1 = uout0 + (size_t)32 * NP * NS;

  for (int pi = 0; pi < PHI_CH; ++pi) {
    __syncthreads();  // previous R tile consumed (also orders ts4/sws once)
    const float4* rsrc = ((const float4*)Rf) + ((size_t)(pbase + pi) << 10);
#pragma unroll
    for (int t4 = 0; t4 < 4; ++t4) Rs4[t4 * 256 + tid] = rsrc[t4 * 256 + tid];
    __syncthreads();

    float ma = 0.f, mb = 0.f;
#pragma unroll
    for (int d4 = 0; d4 < 16; ++d4) {
      const float4 tv = ts4[pi * 16 + d4];
      float ya0 = tv.x, ya1 = tv.y, ya2 = tv.z, ya3 = tv.w;
      float yb0 = tv.x, yb1 = tv.y, yb2 = tv.z, yb3 = tv.w;
#pragma unroll
      for (int e4 = d4; e4 < 16; ++e4) {
        const float4 r0 = Rs4[(d4 * 4 + 0) * 16 + e4];
        const float4 r1 = Rs4[(d4 * 4 + 1) * 16 + e4];
        const float4 r2 = Rs4[(d4 * 4 + 2) * 16 + e4];
        const float4 r3 = Rs4[(d4 * 4 + 3) * 16 + e4];
        const float4 qa_ = qa[e4];
        const float4 qb_ = qb[e4];
        ya0 += r0.x * qa_.x; ya0 += r0.y * qa_.y; ya0 += r0.z * qa_.z; ya0 += r0.w * qa_.w;
        ya1 += r1.x * qa_.x; ya1 += r1.y * qa_.y; ya1 += r1.z * qa_.z; ya1 += r1.w * qa_.w;
        ya2 += r2.x * qa_.x; ya2 += r2.y * qa_.y; ya2 += r2.z * qa_.z; ya2 += r2.w * qa_.w;
        ya3 += r3.x * qa_.x; ya3 += r3.y * qa_.y; ya3 += r3.z * qa_.z; ya3 += r3.w * qa_.w;
        yb0 += r0.x * qb_.x; yb0 += r0.y * qb_.y; yb0 += r0.z * qb_.z; yb0 += r0.w * qb_.w;
        yb1 += r1.x * qb_.x; yb1 += r1.y * qb_.y; yb1 += r1.z * qb_.z; yb1 += r1.w * qb_.w;
        yb2 += r2.x * qb_.x; yb2 += r2.y * qb_.y; yb2 += r2.z * qb_.z; yb2 += r2.w * qb_.w;
        yb3 += r3.x * qb_.x; yb3 += r3.y * qb_.y; yb3 += r3.z * qb_.z; yb3 += r3.w * qb_.w;
      }
      ma += ya0 * ya0; ma += ya1 * ya1; ma += ya2 * ya2; ma += ya3 * ya3;
      mb += yb0 * yb0; mb += yb1 * yb1; mb += yb2 * yb2; mb += yb3 * yb3;
    }
    const float sw = sws[pi];
    uout0[(size_t)(pbase + pi) << 10] = sw * expf(-0.5f * ma);
    uout1[(size_t)(pbase + pi) << 10] = sw * expf(-0.5f * mb);
  }
}

// ---------------------------------------------------------------------------
// attn: per (bh, 16-row tile):
//   Gram A[16][1024] = Ui^T Uj (fp32, prefetched L2 reads),
//   per-wave (2 rows): exact top-64 threshold (bitwise search, >= keeps
//   ties), rowsum with mask -> inv, COMPACT nonzero kept entries to LDS,
//   then sparse ctx: ctx[r][d] = sum_nz a * V[bh][j][d] (coalesced 256B
//   V-row reads). No dense A@V, no extra barriers after Gram.
// ---------------------------------------------------------------------------
__global__ __launch_bounds__(512) void attn_kernel(
    const float* __restrict__ Ut, const float* __restrict__ V,
    const float* __restrict__ amask, float* __restrict__ ctx) {
  __shared__ float4 At4[16 * 256];   // 64 KB: A tile [16][1024]
  __shared__ float4 Uit4[NP * 4];    // 7 KB: Ui fragments [p][16]
  float* Uit = (float*)Uit4;
  const int tid = threadIdx.x;
  const int i0 = blockIdx.x * 16;
  const int bh = blockIdx.y;
  const int bidx = bh >> 4;
  const int h = bh & 15;
  const float* Ubh = Ut + (size_t)bh * NP * NS;

  for (int idx = tid; idx < NP * 16; idx += 512) {
    const int p = idx >> 4, r = idx & 15;
    Uit[idx] = Ubh[(size_t)p * NS + i0 + r];
  }
  __syncthreads();

  // ---- Gram phase: 512 threads = 4 rowgroups x 128 colgroups, 4x8 micro ----
  {
    const int cg = tid & 127;
    const int rg = tid >> 7;
    const float* ujb = Ubh + cg * 8;
    float acc[4][8];
#pragma unroll
    for (int r = 0; r < 4; ++r)
#pragma unroll
      for (int c = 0; c < 8; ++c) acc[r][c] = 0.f;

    float4 nu0 = *(const float4*)(ujb);
    float4 nu1 = *(const float4*)(ujb + 4);
#define CROW(r, uir)                                                         \
  acc[r][0] += uir * uj0.x; acc[r][1] += uir * uj0.y;                        \
  acc[r][2] += uir * uj0.z; acc[r][3] += uir * uj0.w;                        \
  acc[r][4] += uir * uj1.x; acc[r][5] += uir * uj1.y;                        \
  acc[r][6] += uir * uj1.z; acc[r][7] += uir * uj1.w;
#pragma unroll 2
    for (int p = 0; p < NP - 1; ++p) {
      const float4 uj0 = nu0, uj1 = nu1;
      nu0 = *(const float4*)(ujb + (size_t)(p + 1) * NS);
      nu1 = *(const float4*)(ujb + (size_t)(p + 1) * NS + 4);
      const float4 ui = Uit4[p * 4 + rg];
      CROW(0, ui.x) CROW(1, ui.y) CROW(2, ui.z) CROW(3, ui.w)
    }
    {
      const float4 uj0 = nu0, uj1 = nu1;
      const float4 ui = Uit4[(NP - 1) * 4 + rg];
      CROW(0, ui.x) CROW(1, ui.y) CROW(2, ui.z) CROW(3, ui.w)
    }
#undef CROW
#pragma unroll
    for (int r = 0; r < 4; ++r) {
      At4[((rg * 4 + r) << 8) + cg * 2] =
          make_float4(acc[r][0], acc[r][1], acc[r][2], acc[r][3]);
      At4[((rg * 4 + r) << 8) + cg * 2 + 1] =
          make_float4(acc[r][4], acc[r][5], acc[r][6], acc[r][7]);
    }
  }
  __syncthreads();

  // ---- per-wave: exact top-64 thr, rowsum->inv, compact, sparse ctx ----
  {
    const int wv = tid >> 6, lane = tid & 63;
    const float* Vb = V + ((size_t)bh << 16);           // [s][64]
    const float4* mrow4 = (const float4*)(amask + (bidx << 10) + (lane << 4));
    int cnts[2];

#pragma unroll
    for (int rr = 0; rr < 2; ++rr) {
      const int r = wv * 2 + rr;
      float fv[16], fm[16];
#pragma unroll
      for (int k4 = 0; k4 < 4; ++k4) {
        const float4 v = At4[(r << 8) + lane * 4 + k4];
        const float4 mk = mrow4[k4];
        fv[k4 * 4 + 0] = v.x; fv[k4 * 4 + 1] = v.y;
        fv[k4 * 4 + 2] = v.z; fv[k4 * 4 + 3] = v.w;
        fm[k4 * 4 + 0] = v.x * mk.x; fm[k4 * 4 + 1] = v.y * mk.y;
        fm[k4 * 4 + 2] = v.z * mk.z; fm[k4 * 4 + 3] = v.w * mk.w;
      }
      // all values >= 0 -> uint order == float order; find exact 64th-largest
      unsigned c = 0u;
      for (int bit = 30; bit >= 0; --bit) {
        const unsigned cand = c | (1u << bit);
        int cnt = 0;
#pragma unroll
        for (int k = 0; k < 16; ++k)
          cnt += (int)__popcll(__ballot(__float_as_uint(fv[k]) >= cand));
        if (cnt >= NTOPK) c = cand;
      }
      const float thr = __uint_as_float(c);
      float ssum = 0.f;
#pragma unroll
      for (int k = 0; k < 16; ++k) ssum += (fv[k] >= thr) ? fm[k] : 0.f;
#pragma unroll
      for (int off = 32; off > 0; off >>= 1) ssum += __shfl_xor(ssum, off, 64);
      const float inv = 1.0f / fmaxf(ssum, 1e-12f);

      // compact kept nonzeros into this row's (now dead) At4 storage
      float* nzv = (float*)&At4[r << 8];          // 128 floats
      int* nzi = (int*)(((float*)&At4[r << 8]) + NZCAP);
      unsigned cnt = 0;
#pragma unroll
      for (int k = 0; k < 16; ++k) {
        const bool keep = (fv[k] >= thr) && (fm[k] > 0.f);
        const unsigned long long b = __ballot(keep);
        if (keep) {
          const unsigned pos = cnt + (unsigned)__popcll(b & ((1ull << lane) - 1ull));
          if (pos < NZCAP) {
            nzi[pos] = 16 * lane + k;
            nzv[pos] = fm[k] * inv;
          }
        }
        cnt += (unsigned)__popcll(b);
      }
      cnts[rr] = (int)(cnt < NZCAP ? cnt : NZCAP);
    }

    // sparse ctx for the wave's two rows
#pragma unroll
    for (int rr = 0; rr < 2; ++rr) {
      const int r = wv * 2 + rr;
      const float* nzv = (const float*)&At4[r << 8];
      const int* nzi = (const int*)(((const float*)&At4[r << 8]) + NZCAP);
      const int n = cnts[rr];
      float a0 = 0.f, a1 = 0.f, a2 = 0.f, a3 = 0.f;
      int t = 0;
      for (; t + 4 <= n; t += 4) {
        const int j0 = nzi[t], j1 = nzi[t + 1], j2 = nzi[t + 2], j3 = nzi[t + 3];
        const float w0 = nzv[t], w1 = nzv[t + 1], w2 = nzv[t + 2], w3 = nzv[t + 3];
        a0 += w0 * Vb[(j0 << 6) + lane];
        a1 += w1 * Vb[(j1 << 6) + lane];
        a2 += w2 * Vb[(j2 << 6) + lane];
        a3 += w3 * Vb[(j3 << 6) + lane];
      }
      for (; t < n; ++t) a0 += nzv[t] * Vb[(nzi[t] << 6) + lane];
      const float s = (a0 + a1) + (a2 + a3);
      ctx[(size_t)((bidx << 10) + i0 + r) * 1024 + (h << 6) + lane] = s;
    }
  }
}

// ---------------------------------------------------------------------------
extern "C" void kernel_launch(void* const* d_in, const int* in_sizes, int n_in,
                              void* d_out, int out_size, void* d_ws,
                              size_t ws_size, hipStream_t stream) {
  (void)in_sizes; (void)n_in; (void)out_size; (void)ws_size;
  const float* hs    = (const float*)d_in[0];
  const float* amask = (const float*)d_in[1];
  const float* Wq    = (const float*)d_in[2];
  const float* bq    = (const float*)d_in[3];
  // d_in[4], d_in[5] = Wk, bk : projected-but-unused in the reference
  const float* Wv    = (const float*)d_in[6];
  const float* bv    = (const float*)d_in[7];
  const float* Wo    = (const float*)d_in[8];
  const float* bo    = (const float*)d_in[9];
  const float* mu    = (const float*)d_in[10];
  const float* prec  = (const float*)d_in[11];
  const float* spw   = (const float*)d_in[12];
  float* out = (float*)d_out;

  float* w    = (float*)d_ws;
  float* Q    = w;                 // 4,194,304 floats [(b h s)][64]
  float* V    = w + 4194304;       // 4,194,304 floats [bh][s][64] (after phi)
  float* Rf   = w + 4194304;       // 458,752 floats — alive only until phi done
  float* tneg = w + 4653056;       // 7,168
  float* swg  = w + 4660224;       // 112
  float* Ut   = w + 8388608;       // 7,340,032 floats [(b h p)][s]
  float* ctxb = w;                 // reuse Q region (Q dead after phi)

  prep_kernel<<<dim3(NP), dim3(64), 0, stream>>>(mu, prec, spw, Rf, tneg, swg);
  gemm128<0><<<dim3(16, 32), dim3(256), 0, stream>>>(hs, Wq, bq, Q);
  phi_kernel<<<dim3(128, 8), dim3(256), 0, stream>>>(Q, Rf, tneg, swg, Ut);
  gemm128<1><<<dim3(16, 32), dim3(256), 0, stream>>>(hs, Wv, bv, V);
  attn_kernel<<<dim3(64, 64), dim3(512), 0, stream>>>(Ut, V, amask, ctxb);
  gemm128<2><<<dim3(16, 32), dim3(256), 0, stream>>>(ctxb, Wo, bo, out);
}

// Round 4
// 1162.009 us; speedup vs baseline: 2.5903x; 1.1191x over previous
//
#include <hip/hip_runtime.h>
#include <cstdint>
#include <cstddef>

// Problem constants (fixed by the reference)
#define NB 4
#define NS 1024
#define ND 1024
#define NH 16
#define NDH 64
#define NP 112
#define NTOPK 64
#define NZCAP 128  // per-row compacted nonzero capacity

typedef _Float16 f16x8 __attribute__((ext_vector_type(8)));
typedef float f32x4 __attribute__((ext_vector_type(4)));

__device__ __forceinline__ float dot4(float4 a, float4 b) {
  return (a.x * b.x + a.y * b.y) + (a.z * b.z + a.w * b.w);
}

// ---------------------------------------------------------------------------
// prep: per splat, fp64 Cholesky P = L L^T. Emits fp16-split upper-triangular
// R (R[d][e] = L[e][d], e>=d) as Rh + Rl*2^-11 (lo pre-scaled x2048 so it
// stays in fp16 normal range), tneg[d] = -(R mu)_d (fp32), sw = sqrt(w).
// Runs AFTER split_q: writes land in the (dead) Q fp32 region.
// ---------------------------------------------------------------------------
__global__ __launch_bounds__(64) void prep_kernel(
    const float* __restrict__ mu, const float* __restrict__ prec,
    const float* __restrict__ spw, _Float16* __restrict__ Rh,
    _Float16* __restrict__ Rl, float* __restrict__ tneg,
    float* __restrict__ swg) {
  __shared__ double A[64][64];  // 32 KB
  const int p = blockIdx.x, t = threadIdx.x;
  for (int e = 0; e < 64; ++e)
    A[t][e] = (double)prec[((size_t)p * 64 + t) * 64 + e];
  __syncthreads();
  for (int k = 0; k < 64; ++k) {
    if (t == k) A[k][k] = sqrt(A[k][k]);
    __syncthreads();
    if (t > k) A[t][k] /= A[k][k];
    __syncthreads();
    if (t > k) {
      const double lik = A[t][k];
      for (int j = k + 1; j <= t; ++j) A[t][j] -= lik * A[j][k];
    }
    __syncthreads();
  }
  // row t (dim d = t): R[t][e] = L[e][t] for e>=t else 0; fp16 split
  _Float16* rh = Rh + ((size_t)p << 12) + (t << 6);
  _Float16* rl = Rl + ((size_t)p << 12) + (t << 6);
  for (int e = 0; e < 64; ++e) {
    const float rv = (e >= t) ? (float)A[e][t] : 0.f;
    const _Float16 h = (_Float16)rv;
    rh[e] = h;
    rl[e] = (_Float16)((rv - (float)h) * 2048.0f);
  }
  double s = 0.0;
  for (int e = t; e < 64; ++e) s += A[e][t] * (double)mu[p * 64 + e];
  tneg[p * 64 + t] = (float)(-s);
  if (t == 0) swg[p] = sqrtf(spw[p]);
}

// ---------------------------------------------------------------------------
// split_q: fp32 Q -> fp16 hi + (lo * 2048)
// ---------------------------------------------------------------------------
__global__ __launch_bounds__(256) void split_q(
    const float* __restrict__ Q, _Float16* __restrict__ Qh,
    _Float16* __restrict__ Ql) {
  const int i = (blockIdx.x * 256 + threadIdx.x) * 8;
  const float4 a = *(const float4*)(Q + i);
  const float4 b = *(const float4*)(Q + i + 4);
  const float v[8] = {a.x, a.y, a.z, a.w, b.x, b.y, b.z, b.w};
  f16x8 hv, lv;
#pragma unroll
  for (int j = 0; j < 8; ++j) {
    const _Float16 h = (_Float16)v[j];
    hv[j] = h;
    lv[j] = (_Float16)((v[j] - (float)h) * 2048.0f);
  }
  *(f16x8*)(Qh + i) = hv;
  *(f16x8*)(Ql + i) = lv;
}

// ---------------------------------------------------------------------------
// gemm128: C[m,n] = X[m,:1024] @ W[:1024,n] + bias[n]; tile 128(M) x 64(N),
// 256 threads, micro 8x4, K-step 16.
// MODE 0: head-split layout [(b*H+h)*S+s][d], scaled by 0.125 (Q)
// MODE 1: head-split layout, no scale (V)
// MODE 2: plain row-major (output projection)
// ---------------------------------------------------------------------------
template <int MODE>
__global__ __launch_bounds__(256) void gemm128(
    const float* __restrict__ X, const float* __restrict__ W,
    const float* __restrict__ bias, float* __restrict__ dst) {
  __shared__ __align__(16) float As[16][132];  // [k][m] padded
  __shared__ __align__(16) float Bs[16][68];   // [k][n] padded
  const int tid = threadIdx.x;
  const int n0 = blockIdx.x * 64;
  const int m0 = blockIdx.y * 128;
  const int tr = tid >> 4, tc = tid & 15;
  const int r0 = tr * 8, c0 = tc * 4;
  const int lm = tid >> 2, lk4 = (tid & 3) << 2;   // X staging
  const int wk = tid >> 4, wn4 = (tid & 15) << 2;  // W staging

  float acc[8][4];
#pragma unroll
  for (int i = 0; i < 8; ++i)
#pragma unroll
    for (int j = 0; j < 4; ++j) acc[i][j] = 0.f;

  for (int k0 = 0; k0 < 1024; k0 += 16) {
    const float4 xa = *(const float4*)(X + (size_t)(m0 + lm) * 1024 + k0 + lk4);
    const float4 xb = *(const float4*)(X + (size_t)(m0 + 64 + lm) * 1024 + k0 + lk4);
    const float4 wb = *(const float4*)(W + (size_t)(k0 + wk) * 1024 + n0 + wn4);
    __syncthreads();  // previous tile consumed
    As[lk4 + 0][lm] = xa.x; As[lk4 + 1][lm] = xa.y;
    As[lk4 + 2][lm] = xa.z; As[lk4 + 3][lm] = xa.w;
    As[lk4 + 0][lm + 64] = xb.x; As[lk4 + 1][lm + 64] = xb.y;
    As[lk4 + 2][lm + 64] = xb.z; As[lk4 + 3][lm + 64] = xb.w;
    *(float4*)&Bs[wk][wn4] = wb;
    __syncthreads();
#pragma unroll
    for (int kk = 0; kk < 16; ++kk) {
      const float4 a0 = *(const float4*)&As[kk][r0];
      const float4 a1 = *(const float4*)&As[kk][r0 + 4];
      const float4 b = *(const float4*)&Bs[kk][c0];
#define FMAROW(idx, av)                                                      \
  acc[idx][0] += av * b.x; acc[idx][1] += av * b.y;                          \
  acc[idx][2] += av * b.z; acc[idx][3] += av * b.w;
      FMAROW(0, a0.x) FMAROW(1, a0.y) FMAROW(2, a0.z) FMAROW(3, a0.w)
      FMAROW(4, a1.x) FMAROW(5, a1.y) FMAROW(6, a1.z) FMAROW(7, a1.w)
#undef FMAROW
    }
  }

  const float4 bv = *(const float4*)(bias + n0 + c0);
  const int token0 = m0 + r0;     // 8 consecutive tokens
  const int bidx = token0 >> 10;  // tile never straddles b (128 | 1024)
  if (MODE == 0 || MODE == 1) {
    const int h = n0 >> 6;
    const float sc = (MODE == 0) ? 0.125f : 1.0f;
#pragma unroll
    for (int i = 0; i < 8; ++i) {
      const int s = (token0 & 1023) + i;
      float4 o;
      o.x = (acc[i][0] + bv.x) * sc;
      o.y = (acc[i][1] + bv.y) * sc;
      o.z = (acc[i][2] + bv.z) * sc;
      o.w = (acc[i][3] + bv.w) * sc;
      *(float4*)(dst + ((((size_t)bidx * NH + h) * NS + s) << 6) + c0) = o;
    }
  } else {
#pragma unroll
    for (int i = 0; i < 8; ++i) {
      float4 o = make_float4(acc[i][0] + bv.x, acc[i][1] + bv.y,
                             acc[i][2] + bv.z, acc[i][3] + bv.w);
      *(float4*)(dst + (size_t)(token0 + i) * 1024 + n0 + c0) = o;
    }
  }
}

// ---------------------------------------------------------------------------
// phi via MFMA (fp16x2 split, fp32-faithful to ~2^-22):
//   D[d][tok] = sum_e R[d][e] Q[tok][e], acc_main = Rh*Qh (+ tneg init),
//   acc_corr = Rh*Ql' + Rl'*Qh (lo pre-scaled x2048), y = main + corr/2048,
//   m[tok] = sum_d y^2 via 2x shfl_xor, Ut = sw * exp(-0.5 m).
// Wave = 32 tokens (2 N-tiles); block = 4 waves = 128 tokens; loop 112 splats.
// A-frags (R) read from global (L1/L2-hot); upper-triangular R skips the
// (dtile>=2, kchunk=0) combos. No LDS.
// ---------------------------------------------------------------------------
__global__ __launch_bounds__(256) void phi_mfma(
    const _Float16* __restrict__ Qh, const _Float16* __restrict__ Ql,
    const _Float16* __restrict__ Rh, const _Float16* __restrict__ Rl,
    const float* __restrict__ tneg, const float* __restrict__ swg,
    float* __restrict__ Ut) {
  const int tid = threadIdx.x;
  const int lane = tid & 63, wv = tid >> 6;
  const int l15 = lane & 15, lhi = lane >> 4;
  const int tb = blockIdx.x * 128 + wv * 32;
  const int bh = tb >> 10;
  const int stb = tb & 1023;

  // B-frags (Q), loop-invariant across splats: [Ttile][kchunk][hi/lo]
  f16x8 qb[2][2][2];
#pragma unroll
  for (int T = 0; T < 2; ++T)
#pragma unroll
    for (int c = 0; c < 2; ++c) {
      const size_t off = ((size_t)(tb + T * 16 + l15) << 6) + c * 32 + lhi * 8;
      qb[T][c][0] = *(const f16x8*)(Qh + off);
      qb[T][c][1] = *(const f16x8*)(Ql + off);
    }

  float* ubase = Ut + (size_t)bh * NP * NS;
  const int tokoff = stb + ((lane >> 4) << 4) + l15;  // valid for lane<32

  for (int p = 0; p < NP; ++p) {
    const _Float16* rh = Rh + ((size_t)p << 12);
    const _Float16* rl = Rl + ((size_t)p << 12);
    const float* tn = tneg + (p << 6);

    f32x4 accM[4][2], accC[4][2];
#pragma unroll
    for (int mt = 0; mt < 4; ++mt) {
      const float4 t4 = *(const float4*)(tn + mt * 16 + lhi * 4);
      const f32x4 ti = {t4.x, t4.y, t4.z, t4.w};
      accM[mt][0] = ti; accM[mt][1] = ti;
      const f32x4 z = {0.f, 0.f, 0.f, 0.f};
      accC[mt][0] = z; accC[mt][1] = z;
    }

#pragma unroll
    for (int mt = 0; mt < 4; ++mt) {
#pragma unroll
      for (int c = 0; c < 2; ++c) {
        if (mt >= 2 && c == 0) continue;  // upper-tri: R[d>=32][e<32] == 0
        const size_t ro = ((size_t)(mt * 16 + l15) << 6) + c * 32 + lhi * 8;
        const f16x8 ah = *(const f16x8*)(rh + ro);
        const f16x8 al = *(const f16x8*)(rl + ro);
#pragma unroll
        for (int T = 0; T < 2; ++T) {
          accM[mt][T] = __builtin_amdgcn_mfma_f32_16x16x32_f16(
              ah, qb[T][c][0], accM[mt][T], 0, 0, 0);
          accC[mt][T] = __builtin_amdgcn_mfma_f32_16x16x32_f16(
              ah, qb[T][c][1], accC[mt][T], 0, 0, 0);
          accC[mt][T] = __builtin_amdgcn_mfma_f32_16x16x32_f16(
              al, qb[T][c][0], accC[mt][T], 0, 0, 0);
        }
      }
    }

    float sq0 = 0.f, sq1 = 0.f;
#pragma unroll
    for (int mt = 0; mt < 4; ++mt)
#pragma unroll
      for (int r = 0; r < 4; ++r) {
        const float y0 = accM[mt][0][r] + accC[mt][0][r] * 4.8828125e-4f;
        const float y1 = accM[mt][1][r] + accC[mt][1][r] * 4.8828125e-4f;
        sq0 += y0 * y0;
        sq1 += y1 * y1;
      }
    sq0 += __shfl_xor(sq0, 16, 64); sq0 += __shfl_xor(sq0, 32, 64);
    sq1 += __shfl_xor(sq1, 16, 64); sq1 += __shfl_xor(sq1, 32, 64);
    const float sw = swg[p];
    const float u = sw * expf(-0.5f * ((lane < 16) ? sq0 : sq1));
    if (lane < 32) ubase[(size_t)p * NS + tokoff] = u;
  }
}

// ---------------------------------------------------------------------------
// attn: per (bh, 16-row tile):
//   Gram A[16][1024] = Ui^T Uj, per-wave exact top-64 threshold (bitwise
//   search with exact-64 early exit -> identical kept set), rowsum with
//   mask -> inv, compact nonzeros, sparse ctx via coalesced V-row reads.
// Grid is XCD-swizzled 1-D: id = (bh&7) + 8*(tile + 64*(bh>>3)) so all 64
// tiles of one bh share an XCD's L2 (Ut slice stays resident).
// ---------------------------------------------------------------------------
__global__ __launch_bounds__(512) void attn_kernel(
    const float* __restrict__ Ut, const float* __restrict__ V,
    const float* __restrict__ amask, float* __restrict__ ctx) {
  __shared__ float4 At4[16 * 256];   // 64 KB: A tile [16][1024]
  __shared__ float4 Uit4[NP * 4];    // 7 KB: Ui fragments [p][16]
  float* Uit = (float*)Uit4;
  const int tid = threadIdx.x;
  const int id = blockIdx.x;
  const int bh = ((id >> 9) << 3) | (id & 7);
  const int i0 = ((id >> 3) & 63) * 16;
  const int bidx = bh >> 4;
  const int h = bh & 15;
  const float* Ubh = Ut + (size_t)bh * NP * NS;

  for (int idx = tid; idx < NP * 16; idx += 512) {
    const int p = idx >> 4, r = idx & 15;
    Uit[idx] = Ubh[(size_t)p * NS + i0 + r];
  }
  __syncthreads();

  // ---- Gram phase: 512 threads = 4 rowgroups x 128 colgroups, 4x8 micro ----
  {
    const int cg = tid & 127;
    const int rg = tid >> 7;
    const float* ujb = Ubh + cg * 8;
    float acc[4][8];
#pragma unroll
    for (int r = 0; r < 4; ++r)
#pragma unroll
      for (int c = 0; c < 8; ++c) acc[r][c] = 0.f;

    float4 nu0 = *(const float4*)(ujb);
    float4 nu1 = *(const float4*)(ujb + 4);
#define CROW(r, uir)                                                         \
  acc[r][0] += uir * uj0.x; acc[r][1] += uir * uj0.y;                        \
  acc[r][2] += uir * uj0.z; acc[r][3] += uir * uj0.w;                        \
  acc[r][4] += uir * uj1.x; acc[r][5] += uir * uj1.y;                        \
  acc[r][6] += uir * uj1.z; acc[r][7] += uir * uj1.w;
#pragma unroll 2
    for (int p = 0; p < NP - 1; ++p) {
      const float4 uj0 = nu0, uj1 = nu1;
      nu0 = *(const float4*)(ujb + (size_t)(p + 1) * NS);
      nu1 = *(const float4*)(ujb + (size_t)(p + 1) * NS + 4);
      const float4 ui = Uit4[p * 4 + rg];
      CROW(0, ui.x) CROW(1, ui.y) CROW(2, ui.z) CROW(3, ui.w)
    }
    {
      const float4 uj0 = nu0, uj1 = nu1;
      const float4 ui = Uit4[(NP - 1) * 4 + rg];
      CROW(0, ui.x) CROW(1, ui.y) CROW(2, ui.z) CROW(3, ui.w)
    }
#undef CROW
#pragma unroll
    for (int r = 0; r < 4; ++r) {
      At4[((rg * 4 + r) << 8) + cg * 2] =
          make_float4(acc[r][0], acc[r][1], acc[r][2], acc[r][3]);
      At4[((rg * 4 + r) << 8) + cg * 2 + 1] =
          make_float4(acc[r][4], acc[r][5], acc[r][6], acc[r][7]);
    }
  }
  __syncthreads();

  // ---- per-wave: exact top-64 thr, rowsum->inv, compact, sparse ctx ----
  {
    const int wv = tid >> 6, lane = tid & 63;
    const float* Vb = V + ((size_t)bh << 16);           // [s][64]
    const float4* mrow4 = (const float4*)(amask + (bidx << 10) + (lane << 4));
    int cnts[2];

#pragma unroll
    for (int rr = 0; rr < 2; ++rr) {
      const int r = wv * 2 + rr;
      float fv[16], fm[16];
#pragma unroll
      for (int k4 = 0; k4 < 4; ++k4) {
        const float4 v = At4[(r << 8) + lane * 4 + k4];
        const float4 mk = mrow4[k4];
        fv[k4 * 4 + 0] = v.x; fv[k4 * 4 + 1] = v.y;
        fv[k4 * 4 + 2] = v.z; fv[k4 * 4 + 3] = v.w;
        fm[k4 * 4 + 0] = v.x * mk.x; fm[k4 * 4 + 1] = v.y * mk.y;
        fm[k4 * 4 + 2] = v.z * mk.z; fm[k4 * 4 + 3] = v.w * mk.w;
      }
      // values >= 0 -> uint order == float order. Greedy bitwise search for
      // the largest c with count(v >= c) >= 64. Early exit when the count is
      // exactly 64: the kept set {v >= c} is already the final top-64 set.
      unsigned c = 0u;
      for (int bit = 30; bit >= 0; --bit) {
        const unsigned cand = c | (1u << bit);
        int cnt = 0;
#pragma unroll
        for (int k = 0; k < 16; ++k)
          cnt += (int)__popcll(__ballot(__float_as_uint(fv[k]) >= cand));
        if (cnt >= NTOPK) {
          c = cand;
          if (cnt == NTOPK) break;
        }
      }
      const float thr = __uint_as_float(c);
      float ssum = 0.f;
#pragma unroll
      for (int k = 0; k < 16; ++k) ssum += (fv[k] >= thr) ? fm[k] : 0.f;
#pragma unroll
      for (int off = 32; off > 0; off >>= 1) ssum += __shfl_xor(ssum, off, 64);
      const float inv = 1.0f / fmaxf(ssum, 1e-12f);

      // compact kept nonzeros into this row's (now dead) At4 storage
      float* nzv = (float*)&At4[r << 8];          // 128 floats
      int* nzi = (int*)(((float*)&At4[r << 8]) + NZCAP);
      unsigned cnt = 0;
#pragma unroll
      for (int k = 0; k < 16; ++k) {
        const bool keep = (fv[k] >= thr) && (fm[k] > 0.f);
        const unsigned long long b = __ballot(keep);
        if (keep) {
          const unsigned pos = cnt + (unsigned)__popcll(b & ((1ull << lane) - 1ull));
          if (pos < NZCAP) {
            nzi[pos] = 16 * lane + k;
            nzv[pos] = fm[k] * inv;
          }
        }
        cnt += (unsigned)__popcll(b);
      }
      cnts[rr] = (int)(cnt < NZCAP ? cnt : NZCAP);
    }

    // sparse ctx for the wave's two rows
#pragma unroll
    for (int rr = 0; rr < 2; ++rr) {
      const int r = wv * 2 + rr;
      const float* nzv = (const float*)&At4[r << 8];
      const int* nzi = (const int*)(((const float*)&At4[r << 8]) + NZCAP);
      const int n = cnts[rr];
      float a0 = 0.f, a1 = 0.f, a2 = 0.f, a3 = 0.f;
      int t = 0;
      for (; t + 4 <= n; t += 4) {
        const int j0 = nzi[t], j1 = nzi[t + 1], j2 = nzi[t + 2], j3 = nzi[t + 3];
        const float w0 = nzv[t], w1 = nzv[t + 1], w2 = nzv[t + 2], w3 = nzv[t + 3];
        a0 += w0 * Vb[(j0 << 6) + lane];
        a1 += w1 * Vb[(j1 << 6) + lane];
        a2 += w2 * Vb[(j2 << 6) + lane];
        a3 += w3 * Vb[(j3 << 6) + lane];
      }
      for (; t < n; ++t) a0 += nzv[t] * Vb[(nzi[t] << 6) + lane];
      const float s = (a0 + a1) + (a2 + a3);
      ctx[(size_t)((bidx << 10) + i0 + r) * 1024 + (h << 6) + lane] = s;
    }
  }
}

// ---------------------------------------------------------------------------
extern "C" void kernel_launch(void* const* d_in, const int* in_sizes, int n_in,
                              void* d_out, int out_size, void* d_ws,
                              size_t ws_size, hipStream_t stream) {
  (void)in_sizes; (void)n_in; (void)out_size; (void)ws_size;
  const float* hs    = (const float*)d_in[0];
  const float* amask = (const float*)d_in[1];
  const float* Wq    = (const float*)d_in[2];
  const float* bq    = (const float*)d_in[3];
  // d_in[4], d_in[5] = Wk, bk : projected-but-unused in the reference
  const float* Wv    = (const float*)d_in[6];
  const float* bv    = (const float*)d_in[7];
  const float* Wo    = (const float*)d_in[8];
  const float* bo    = (const float*)d_in[9];
  const float* mu    = (const float*)d_in[10];
  const float* prec  = (const float*)d_in[11];
  const float* spw   = (const float*)d_in[12];
  float* out = (float*)d_out;

  // Region A [0 .. 4,194,304): Q fp32 -> (after split_q) Rh/Rl/tneg/swg ->
  //                            (after phi) ctxb
  // Region B [4,194,304 .. 8,388,608): Qh/Ql fp16 -> (after phi) V fp32
  // Region C [8,388,608 .. 15,728,640): Ut
  float* w = (float*)d_ws;
  float* Q        = w;
  _Float16* Rh    = (_Float16*)w;                  // 458,752 halves
  _Float16* Rl    = (_Float16*)(w + 229376);
  float* tneg     = w + 458752;
  float* swg      = w + 465920;
  float* ctxb     = w;
  _Float16* Qh    = (_Float16*)(w + 4194304);      // 4,194,304 halves
  _Float16* Ql    = (_Float16*)(w + 6291456);
  float* V        = w + 4194304;
  float* Ut       = w + 8388608;

  gemm128<0><<<dim3(16, 32), dim3(256), 0, stream>>>(hs, Wq, bq, Q);
  split_q<<<dim3(2048), dim3(256), 0, stream>>>(Q, Qh, Ql);
  prep_kernel<<<dim3(NP), dim3(64), 0, stream>>>(mu, prec, spw, Rh, Rl, tneg, swg);
  phi_mfma<<<dim3(512), dim3(256), 0, stream>>>(Qh, Ql, Rh, Rl, tneg, swg, Ut);
  gemm128<1><<<dim3(16, 32), dim3(256), 0, stream>>>(hs, Wv, bv, V);
  attn_kernel<<<dim3(4096), dim3(512), 0, stream>>>(Ut, V, amask, ctxb);
  gemm128<2><<<dim3(16, 32), dim3(256), 0, stream>>>(ctxb, Wo, bo, out);
}

// Round 6
// 929.400 us; speedup vs baseline: 3.2386x; 1.2503x over previous
//
#include <hip/hip_runtime.h>
#include <cstdint>
#include <cstddef>

// Problem constants (fixed by the reference)
#define NB 4
#define NS 1024
#define ND 1024
#define NH 16
#define NDH 64
#define NP 112
#define NTOPK 64
#define NZCAP 128   // per-row compacted nonzero capacity
#define PCH 14      // splats per phi chunk (8 chunks)

typedef _Float16 f16x8 __attribute__((ext_vector_type(8)));
typedef float f32x4 __attribute__((ext_vector_type(4)));

__device__ __forceinline__ float dot4(float4 a, float4 b) {
  return (a.x * b.x + a.y * b.y) + (a.z * b.z + a.w * b.w);
}

// ---------------------------------------------------------------------------
// prep: per splat, fp64 Cholesky P = L L^T. Emits fp16-split upper-triangular
// R (R[d][e] = L[e][d], e>=d) as Rh + Rl*2^-11 (lo pre-scaled x2048),
// tneg[d] = -(R mu)_d (fp32), sw = sqrt(splat_w).
// ---------------------------------------------------------------------------
__global__ __launch_bounds__(64) void prep_kernel(
    const float* __restrict__ mu, const float* __restrict__ prec,
    const float* __restrict__ spw, _Float16* __restrict__ Rh,
    _Float16* __restrict__ Rl, float* __restrict__ tneg,
    float* __restrict__ swg) {
  __shared__ double A[64][64];  // 32 KB
  const int p = blockIdx.x, t = threadIdx.x;
  for (int e = 0; e < 64; ++e)
    A[t][e] = (double)prec[((size_t)p * 64 + t) * 64 + e];
  __syncthreads();
  for (int k = 0; k < 64; ++k) {
    if (t == k) A[k][k] = sqrt(A[k][k]);
    __syncthreads();
    if (t > k) A[t][k] /= A[k][k];
    __syncthreads();
    if (t > k) {
      const double lik = A[t][k];
      for (int j = k + 1; j <= t; ++j) A[t][j] -= lik * A[j][k];
    }
    __syncthreads();
  }
  _Float16* rh = Rh + ((size_t)p << 12) + (t << 6);
  _Float16* rl = Rl + ((size_t)p << 12) + (t << 6);
  for (int e = 0; e < 64; ++e) {
    const float rv = (e >= t) ? (float)A[e][t] : 0.f;
    const _Float16 h = (_Float16)rv;
    rh[e] = h;
    rl[e] = (_Float16)((rv - (float)h) * 2048.0f);
  }
  double s = 0.0;
  for (int e = t; e < 64; ++e) s += A[e][t] * (double)mu[p * 64 + e];
  tneg[p * 64 + t] = (float)(-s);
  if (t == 0) swg[p] = sqrtf(spw[p]);
}

// ---------------------------------------------------------------------------
// split_x: fp32 -> fp16 hi + (lo * 2048), elementwise (8 elems/thread)
// ---------------------------------------------------------------------------
__global__ __launch_bounds__(256) void split_x(
    const float* __restrict__ X, _Float16* __restrict__ Xh,
    _Float16* __restrict__ Xl) {
  const size_t i = ((size_t)blockIdx.x * 256 + threadIdx.x) * 8;
  const float4 a = *(const float4*)(X + i);
  const float4 b = *(const float4*)(X + i + 4);
  const float v[8] = {a.x, a.y, a.z, a.w, b.x, b.y, b.z, b.w};
  f16x8 hv, lv;
#pragma unroll
  for (int j = 0; j < 8; ++j) {
    const _Float16 h = (_Float16)v[j];
    hv[j] = h;
    lv[j] = (_Float16)((v[j] - (float)h) * 2048.0f);
  }
  *(f16x8*)(Xh + i) = hv;
  *(f16x8*)(Xl + i) = lv;
}

// ---------------------------------------------------------------------------
// transpose_split: W[k][n] fp32 (1024x1024) -> Th/Tl [n][k] fp16 split
// ---------------------------------------------------------------------------
__global__ __launch_bounds__(256) void transpose_split(
    const float* __restrict__ W, _Float16* __restrict__ Th,
    _Float16* __restrict__ Tl) {
  __shared__ float T[64][65];
  const int tid = threadIdx.x;
  const int k0 = blockIdx.x * 64, n0 = blockIdx.y * 64;
  const int c = tid & 63, rb = tid >> 6;
#pragma unroll 4
  for (int i = 0; i < 16; ++i) {
    const int r = rb * 16 + i;
    T[r][c] = W[(size_t)(k0 + r) * 1024 + n0 + c];
  }
  __syncthreads();
#pragma unroll 4
  for (int i = 0; i < 16; ++i) {
    const int r = rb * 16 + i;               // local n
    const float v = T[c][r];                 // = W[k0+c][n0+r]
    const _Float16 h = (_Float16)v;
    Th[(size_t)(n0 + r) * 1024 + k0 + c] = h;
    Tl[(size_t)(n0 + r) * 1024 + k0 + c] = (_Float16)((v - (float)h) * 2048.0f);
  }
}

// ---------------------------------------------------------------------------
// gemmq_mfma: Q = (hs @ Wq + bq) * 0.125 via fp16-split MFMA (hh + hl + lh),
// output written directly as fp16-split Qh/Ql in [bh][s][d] layout.
// Block 256 thr = 4 waves; wave tile 32(M) x 64(N); K=1024 step 32; no LDS.
// ---------------------------------------------------------------------------
__global__ __launch_bounds__(256, 2) void gemmq_mfma(
    const _Float16* __restrict__ Xh, const _Float16* __restrict__ Xl,
    const _Float16* __restrict__ Wth, const _Float16* __restrict__ Wtl,
    const float* __restrict__ bias, _Float16* __restrict__ QhO,
    _Float16* __restrict__ QlO) {
  const int tid = threadIdx.x, lane = tid & 63, wv = tid >> 6;
  const int l15 = lane & 15, lhi = lane >> 4;
  const int n0 = blockIdx.x * 64;
  const int m0 = blockIdx.y * 128 + wv * 32;

  f32x4 aM[2][4], aC[2][4];
#pragma unroll
  for (int i = 0; i < 2; ++i)
#pragma unroll
    for (int j = 0; j < 4; ++j) {
      const f32x4 z = {0.f, 0.f, 0.f, 0.f};
      aM[i][j] = z; aC[i][j] = z;
    }

  const _Float16* xh0 = Xh + (size_t)(m0 + l15) * 1024 + lhi * 8;
  const _Float16* xl0 = Xl + (size_t)(m0 + l15) * 1024 + lhi * 8;
  const _Float16* wh0 = Wth + (size_t)(n0 + l15) * 1024 + lhi * 8;
  const _Float16* wl0 = Wtl + (size_t)(n0 + l15) * 1024 + lhi * 8;

#pragma unroll 4
  for (int k0 = 0; k0 < 1024; k0 += 32) {
    f16x8 ah[2], al[2], bh[4], bl[4];
#pragma unroll
    for (int mA = 0; mA < 2; ++mA) {
      ah[mA] = *(const f16x8*)(xh0 + mA * 16384 + k0);
      al[mA] = *(const f16x8*)(xl0 + mA * 16384 + k0);
    }
#pragma unroll
    for (int nB = 0; nB < 4; ++nB) {
      bh[nB] = *(const f16x8*)(wh0 + nB * 16384 + k0);
      bl[nB] = *(const f16x8*)(wl0 + nB * 16384 + k0);
    }
#pragma unroll
    for (int mA = 0; mA < 2; ++mA)
#pragma unroll
      for (int nB = 0; nB < 4; ++nB) {
        aM[mA][nB] = __builtin_amdgcn_mfma_f32_16x16x32_f16(ah[mA], bh[nB], aM[mA][nB], 0, 0, 0);
        aC[mA][nB] = __builtin_amdgcn_mfma_f32_16x16x32_f16(ah[mA], bl[nB], aC[mA][nB], 0, 0, 0);
        aC[mA][nB] = __builtin_amdgcn_mfma_f32_16x16x32_f16(al[mA], bh[nB], aC[mA][nB], 0, 0, 0);
      }
  }

  const float eps = 4.8828125e-4f;  // 2^-11
  const int h = n0 >> 6;
  float bq[4];
#pragma unroll
  for (int nB = 0; nB < 4; ++nB) bq[nB] = bias[n0 + nB * 16 + l15];
#pragma unroll
  for (int mA = 0; mA < 2; ++mA)
#pragma unroll
    for (int nB = 0; nB < 4; ++nB) {
      const int dd = nB * 16 + l15;
#pragma unroll
      for (int r = 0; r < 4; ++r) {
        const int m = m0 + mA * 16 + lhi * 4 + r;
        const int b = m >> 10, s = m & 1023;
        const float v = (aM[mA][nB][r] + aC[mA][nB][r] * eps + bq[nB]) * 0.125f;
        const _Float16 hh = (_Float16)v;
        const size_t o = ((((size_t)b * NH + h) << 10) + s) * 64 + dd;
        QhO[o] = hh;
        QlO[o] = (_Float16)((v - (float)hh) * 2048.0f);
      }
    }
}

// ---------------------------------------------------------------------------
// gemm128 (fp32 VALU): C = X@W + bias; tile 128x64, micro 8x4.
// MODE 1: head-split layout [bh][s][d] (V); MODE 2: row-major (out-proj)
// ---------------------------------------------------------------------------
template <int MODE>
__global__ __launch_bounds__(256) void gemm128(
    const float* __restrict__ X, const float* __restrict__ W,
    const float* __restrict__ bias, float* __restrict__ dst) {
  __shared__ __align__(16) float As[16][132];
  __shared__ __align__(16) float Bs[16][68];
  const int tid = threadIdx.x;
  const int n0 = blockIdx.x * 64;
  const int m0 = blockIdx.y * 128;
  const int tr = tid >> 4, tc = tid & 15;
  const int r0 = tr * 8, c0 = tc * 4;
  const int lm = tid >> 2, lk4 = (tid & 3) << 2;
  const int wk = tid >> 4, wn4 = (tid & 15) << 2;

  float acc[8][4];
#pragma unroll
  for (int i = 0; i < 8; ++i)
#pragma unroll
    for (int j = 0; j < 4; ++j) acc[i][j] = 0.f;

  for (int k0 = 0; k0 < 1024; k0 += 16) {
    const float4 xa = *(const float4*)(X + (size_t)(m0 + lm) * 1024 + k0 + lk4);
    const float4 xb = *(const float4*)(X + (size_t)(m0 + 64 + lm) * 1024 + k0 + lk4);
    const float4 wb = *(const float4*)(W + (size_t)(k0 + wk) * 1024 + n0 + wn4);
    __syncthreads();
    As[lk4 + 0][lm] = xa.x; As[lk4 + 1][lm] = xa.y;
    As[lk4 + 2][lm] = xa.z; As[lk4 + 3][lm] = xa.w;
    As[lk4 + 0][lm + 64] = xb.x; As[lk4 + 1][lm + 64] = xb.y;
    As[lk4 + 2][lm + 64] = xb.z; As[lk4 + 3][lm + 64] = xb.w;
    *(float4*)&Bs[wk][wn4] = wb;
    __syncthreads();
#pragma unroll
    for (int kk = 0; kk < 16; ++kk) {
      const float4 a0 = *(const float4*)&As[kk][r0];
      const float4 a1 = *(const float4*)&As[kk][r0 + 4];
      const float4 b = *(const float4*)&Bs[kk][c0];
#define FMAROW(idx, av)                                                      \
  acc[idx][0] += av * b.x; acc[idx][1] += av * b.y;                          \
  acc[idx][2] += av * b.z; acc[idx][3] += av * b.w;
      FMAROW(0, a0.x) FMAROW(1, a0.y) FMAROW(2, a0.z) FMAROW(3, a0.w)
      FMAROW(4, a1.x) FMAROW(5, a1.y) FMAROW(6, a1.z) FMAROW(7, a1.w)
#undef FMAROW
    }
  }

  const float4 bv = *(const float4*)(bias + n0 + c0);
  const int token0 = m0 + r0;
  const int bidx = token0 >> 10;
  if (MODE == 1) {
    const int h = n0 >> 6;
#pragma unroll
    for (int i = 0; i < 8; ++i) {
      const int s = (token0 & 1023) + i;
      float4 o = make_float4(acc[i][0] + bv.x, acc[i][1] + bv.y,
                             acc[i][2] + bv.z, acc[i][3] + bv.w);
      *(float4*)(dst + ((((size_t)bidx * NH + h) * NS + s) << 6) + c0) = o;
    }
  } else {
#pragma unroll
    for (int i = 0; i < 8; ++i) {
      float4 o = make_float4(acc[i][0] + bv.x, acc[i][1] + bv.y,
                             acc[i][2] + bv.z, acc[i][3] + bv.w);
      *(float4*)(dst + (size_t)(token0 + i) * 1024 + n0 + c0) = o;
    }
  }
}

// ---------------------------------------------------------------------------
// phi v3: m = ||R q + tneg||^2 via MFMA, R double-buffered in LDS with
// XOR-swizzle (source-side on stage, addr-side on read), reg-staged
// load-early/write-late pipeline, 64 tokens/wave, p-chunked grid.
// Grid: 256 token-blocks (x 256 tokens = 65536 = 64 bh x 1024 s) x 8 chunks.
// ---------------------------------------------------------------------------
__global__ __launch_bounds__(256, 2) void phi3(
    const _Float16* __restrict__ Qh, const _Float16* __restrict__ Ql,
    const _Float16* __restrict__ Rh, const _Float16* __restrict__ Rl,
    const float* __restrict__ tneg, const float* __restrict__ swg,
    float* __restrict__ Ut) {
  __shared__ __align__(16) _Float16 RhS[2][4096];  // 8 KB per buf
  __shared__ __align__(16) _Float16 RlS[2][4096];
  __shared__ __align__(16) float tns[PCH * 64];
  __shared__ float sws[PCH];
  const int tid = threadIdx.x, lane = tid & 63, wv = tid >> 6;
  const int l15 = lane & 15, lhi = lane >> 4;
  const int tokbase = blockIdx.x * 256;
  const int tb = tokbase + wv * 64;
  const int pbase = blockIdx.y * PCH;
  const float eps = 4.8828125e-4f;

  for (int i = tid; i < PCH * 16; i += 256)
    ((float4*)tns)[i] = ((const float4*)(tneg + (pbase << 6)))[i];
  if (tid < PCH) sws[tid] = swg[pbase + tid];

  // Q fragments (loop-invariant): [Ttile][kchunk][hi/lo]
  f16x8 qb[4][2][2];
#pragma unroll
  for (int T = 0; T < 4; ++T)
#pragma unroll
    for (int c = 0; c < 2; ++c) {
      const size_t off = ((size_t)(tb + T * 16 + l15) << 6) + c * 32 + lhi * 8;
      qb[T][c][0] = *(const f16x8*)(Qh + off);
      qb[T][c][1] = *(const f16x8*)(Ql + off);
    }

  // stage regs: this thread owns bytes [tid*32, tid*32+32) of each 8KB image
  f16x8 sgH[2], sgL[2];
#define PHI_LOAD(p)                                                          \
  {                                                                          \
    const _Float16* rhp = Rh + ((size_t)(pbase + (p)) << 12);                \
    const _Float16* rlp = Rl + ((size_t)(pbase + (p)) << 12);                \
    _Pragma("unroll") for (int j = 0; j < 2; ++j) {                          \
      const int X = tid * 32 + j * 16;                                       \
      const int src = X ^ (((X >> 7) & 7) << 4);                             \
      sgH[j] = *(const f16x8*)((const char*)rhp + src);                      \
      sgL[j] = *(const f16x8*)((const char*)rlp + src);                      \
    }                                                                        \
  }
#define PHI_WRITE(buf)                                                       \
  {                                                                          \
    _Pragma("unroll") for (int j = 0; j < 2; ++j) {                          \
      const int X = tid * 32 + j * 16;                                       \
      *(f16x8*)((char*)&RhS[buf][0] + X) = sgH[j];                           \
      *(f16x8*)((char*)&RlS[buf][0] + X) = sgL[j];                           \
    }                                                                        \
  }

  PHI_LOAD(0)
  PHI_WRITE(0)

  float* ub = Ut + (((size_t)(tokbase >> 10) * NP) << 10);
  const int sbase = (tb & 1023);

  for (int pi = 0; pi < PCH; ++pi) {
    __syncthreads();  // buf[pi&1] writes visible to all
    const int buf = pi & 1;
    if (pi + 1 < PCH) PHI_LOAD(pi + 1)  // issue early; lands under compute

    float sq0 = 0.f, sq1 = 0.f, sq2 = 0.f, sq3 = 0.f;
#pragma unroll
    for (int mt = 0; mt < 4; ++mt) {
      const float4 tv = *(const float4*)&tns[(pi << 6) + mt * 16 + lhi * 4];
      const f32x4 ti = {tv.x, tv.y, tv.z, tv.w};
      const f32x4 z = {0.f, 0.f, 0.f, 0.f};
      f32x4 aM[4], aC[4];
#pragma unroll
      for (int T = 0; T < 4; ++T) { aM[T] = ti; aC[T] = z; }
#pragma unroll
      for (int c = 0; c < 2; ++c) {
        if (mt >= 2 && c == 0) continue;  // upper-tri zero block
        const int row = mt * 16 + l15;
        int bo = row * 128 + c * 64 + lhi * 16;
        bo ^= ((row & 7) << 4);
        const f16x8 ah = *(const f16x8*)((const char*)&RhS[buf][0] + bo);
        const f16x8 al = *(const f16x8*)((const char*)&RlS[buf][0] + bo);
#pragma unroll
        for (int T = 0; T < 4; ++T) {
          aM[T] = __builtin_amdgcn_mfma_f32_16x16x32_f16(ah, qb[T][c][0], aM[T], 0, 0, 0);
          aC[T] = __builtin_amdgcn_mfma_f32_16x16x32_f16(ah, qb[T][c][1], aC[T], 0, 0, 0);
          aC[T] = __builtin_amdgcn_mfma_f32_16x16x32_f16(al, qb[T][c][0], aC[T], 0, 0, 0);
        }
      }
#pragma unroll
      for (int r = 0; r < 4; ++r) {
        float y;
        y = aM[0][r] + aC[0][r] * eps; sq0 += y * y;
        y = aM[1][r] + aC[1][r] * eps; sq1 += y * y;
        y = aM[2][r] + aC[2][r] * eps; sq2 += y * y;
        y = aM[3][r] + aC[3][r] * eps; sq3 += y * y;
      }
    }
    sq0 += __shfl_xor(sq0, 16, 64); sq0 += __shfl_xor(sq0, 32, 64);
    sq1 += __shfl_xor(sq1, 16, 64); sq1 += __shfl_xor(sq1, 32, 64);
    sq2 += __shfl_xor(sq2, 16, 64); sq2 += __shfl_xor(sq2, 32, 64);
    sq3 += __shfl_xor(sq3, 16, 64); sq3 += __shfl_xor(sq3, 32, 64);
    const float sqs = (lhi == 0) ? sq0 : (lhi == 1) ? sq1 : (lhi == 2) ? sq2 : sq3;
    const float u = sws[pi] * expf(-0.5f * sqs);
    ub[((size_t)(pbase + pi) << 10) + sbase + lane] = u;

    __syncthreads();  // all waves done reading buf before overwrite
    if (pi + 1 < PCH) PHI_WRITE(buf ^ 1)
  }
#undef PHI_LOAD
#undef PHI_WRITE
}

// ---------------------------------------------------------------------------
// attn: Gram A = Ui^T Uj (fp32), exact top-64 threshold (bitwise search,
// early-exit at exact 64), mask, rowsum->inv, compact, sparse ctx.
// XCD-swizzled 1-D grid: id = (bh&7) + 8*(tile + 64*(bh>>3)).
// ---------------------------------------------------------------------------
__global__ __launch_bounds__(512) void attn_kernel(
    const float* __restrict__ Ut, const float* __restrict__ V,
    const float* __restrict__ amask, float* __restrict__ ctx) {
  __shared__ float4 At4[16 * 256];   // 64 KB
  __shared__ float4 Uit4[NP * 4];    // 7 KB
  float* Uit = (float*)Uit4;
  const int tid = threadIdx.x;
  const int id = blockIdx.x;
  const int bh = ((id >> 9) << 3) | (id & 7);
  const int i0 = ((id >> 3) & 63) * 16;
  const int bidx = bh >> 4;
  const int h = bh & 15;
  const float* Ubh = Ut + (size_t)bh * NP * NS;

  for (int idx = tid; idx < NP * 16; idx += 512) {
    const int p = idx >> 4, r = idx & 15;
    Uit[idx] = Ubh[(size_t)p * NS + i0 + r];
  }
  __syncthreads();

  {
    const int cg = tid & 127;
    const int rg = tid >> 7;
    const float* ujb = Ubh + cg * 8;
    float acc[4][8];
#pragma unroll
    for (int r = 0; r < 4; ++r)
#pragma unroll
      for (int c = 0; c < 8; ++c) acc[r][c] = 0.f;

    float4 nu0 = *(const float4*)(ujb);
    float4 nu1 = *(const float4*)(ujb + 4);
#define CROW(r, uir)                                                         \
  acc[r][0] += uir * uj0.x; acc[r][1] += uir * uj0.y;                        \
  acc[r][2] += uir * uj0.z; acc[r][3] += uir * uj0.w;                        \
  acc[r][4] += uir * uj1.x; acc[r][5] += uir * uj1.y;                        \
  acc[r][6] += uir * uj1.z; acc[r][7] += uir * uj1.w;
#pragma unroll 2
    for (int p = 0; p < NP - 1; ++p) {
      const float4 uj0 = nu0, uj1 = nu1;
      nu0 = *(const float4*)(ujb + (size_t)(p + 1) * NS);
      nu1 = *(const float4*)(ujb + (size_t)(p + 1) * NS + 4);
      const float4 ui = Uit4[p * 4 + rg];
      CROW(0, ui.x) CROW(1, ui.y) CROW(2, ui.z) CROW(3, ui.w)
    }
    {
      const float4 uj0 = nu0, uj1 = nu1;
      const float4 ui = Uit4[(NP - 1) * 4 + rg];
      CROW(0, ui.x) CROW(1, ui.y) CROW(2, ui.z) CROW(3, ui.w)
    }
#undef CROW
#pragma unroll
    for (int r = 0; r < 4; ++r) {
      At4[((rg * 4 + r) << 8) + cg * 2] =
          make_float4(acc[r][0], acc[r][1], acc[r][2], acc[r][3]);
      At4[((rg * 4 + r) << 8) + cg * 2 + 1] =
          make_float4(acc[r][4], acc[r][5], acc[r][6], acc[r][7]);
    }
  }
  __syncthreads();

  {
    const int wv = tid >> 6, lane = tid & 63;
    const float* Vb = V + ((size_t)bh << 16);
    const float4* mrow4 = (const float4*)(amask + (bidx << 10) + (lane << 4));
    int cnts[2];

#pragma unroll
    for (int rr = 0; rr < 2; ++rr) {
      const int r = wv * 2 + rr;
      float fv[16], fm[16];
#pragma unroll
      for (int k4 = 0; k4 < 4; ++k4) {
        const float4 v = At4[(r << 8) + lane * 4 + k4];
        const float4 mk = mrow4[k4];
        fv[k4 * 4 + 0] = v.x; fv[k4 * 4 + 1] = v.y;
        fv[k4 * 4 + 2] = v.z; fv[k4 * 4 + 3] = v.w;
        fm[k4 * 4 + 0] = v.x * mk.x; fm[k4 * 4 + 1] = v.y * mk.y;
        fm[k4 * 4 + 2] = v.z * mk.z; fm[k4 * 4 + 3] = v.w * mk.w;
      }
      unsigned c = 0u;
      for (int bit = 30; bit >= 0; --bit) {
        const unsigned cand = c | (1u << bit);
        int cnt = 0;
#pragma unroll
        for (int k = 0; k < 16; ++k)
          cnt += (int)__popcll(__ballot(__float_as_uint(fv[k]) >= cand));
        if (cnt >= NTOPK) {
          c = cand;
          if (cnt == NTOPK) break;
        }
      }
      const float thr = __uint_as_float(c);
      float ssum = 0.f;
#pragma unroll
      for (int k = 0; k < 16; ++k) ssum += (fv[k] >= thr) ? fm[k] : 0.f;
#pragma unroll
      for (int off = 32; off > 0; off >>= 1) ssum += __shfl_xor(ssum, off, 64);
      const float inv = 1.0f / fmaxf(ssum, 1e-12f);

      float* nzv = (float*)&At4[r << 8];
      int* nzi = (int*)(((float*)&At4[r << 8]) + NZCAP);
      unsigned cnt = 0;
#pragma unroll
      for (int k = 0; k < 16; ++k) {
        const bool keep = (fv[k] >= thr) && (fm[k] > 0.f);
        const unsigned long long b = __ballot(keep);
        if (keep) {
          const unsigned pos = cnt + (unsigned)__popcll(b & ((1ull << lane) - 1ull));
          if (pos < NZCAP) {
            nzi[pos] = 16 * lane + k;
            nzv[pos] = fm[k] * inv;
          }
        }
        cnt += (unsigned)__popcll(b);
      }
      cnts[rr] = (int)(cnt < NZCAP ? cnt : NZCAP);
    }

#pragma unroll
    for (int rr = 0; rr < 2; ++rr) {
      const int r = wv * 2 + rr;
      const float* nzv = (const float*)&At4[r << 8];
      const int* nzi = (const int*)(((const float*)&At4[r << 8]) + NZCAP);
      const int n = cnts[rr];
      float a0 = 0.f, a1 = 0.f, a2 = 0.f, a3 = 0.f;
      int t = 0;
      for (; t + 4 <= n; t += 4) {
        const int j0 = nzi[t], j1 = nzi[t + 1], j2 = nzi[t + 2], j3 = nzi[t + 3];
        const float w0 = nzv[t], w1 = nzv[t + 1], w2 = nzv[t + 2], w3 = nzv[t + 3];
        a0 += w0 * Vb[(j0 << 6) + lane];
        a1 += w1 * Vb[(j1 << 6) + lane];
        a2 += w2 * Vb[(j2 << 6) + lane];
        a3 += w3 * Vb[(j3 << 6) + lane];
      }
      for (; t < n; ++t) a0 += nzv[t] * Vb[(nzi[t] << 6) + lane];
      const float s = (a0 + a1) + (a2 + a3);
      ctx[(size_t)((bidx << 10) + i0 + r) * 1024 + (h << 6) + lane] = s;
    }
  }
}

// ---------------------------------------------------------------------------
extern "C" void kernel_launch(void* const* d_in, const int* in_sizes, int n_in,
                              void* d_out, int out_size, void* d_ws,
                              size_t ws_size, hipStream_t stream) {
  (void)in_sizes; (void)n_in; (void)out_size; (void)ws_size;
  const float* hs    = (const float*)d_in[0];
  const float* amask = (const float*)d_in[1];
  const float* Wq    = (const float*)d_in[2];
  const float* bq    = (const float*)d_in[3];
  // d_in[4], d_in[5] = Wk, bk : projected-but-unused in the reference
  const float* Wv    = (const float*)d_in[6];
  const float* bv    = (const float*)d_in[7];
  const float* Wo    = (const float*)d_in[8];
  const float* bo    = (const float*)d_in[9];
  const float* mu    = (const float*)d_in[10];
  const float* prec  = (const float*)d_in[11];
  const float* spw   = (const float*)d_in[12];
  float* out = (float*)d_out;

  // Layout (float offsets), peak = 15,728,640 floats (proven budget):
  //  [0,2M)      Xh          -> dead after gemmq -> ctx (attn)
  //  [2M,4M)     Xl          -> dead after gemmq -> Rh/Rl/tneg/swg (prep) -> ctx
  //  [4M,8M)     Qh/Ql       -> dead after phi   -> V (gemm128<1>)
  //  [8M,15.34M) Wqt (transient, dead after gemmq) then Ut (phi)
  float* w = (float*)d_ws;
  _Float16* Xh   = (_Float16*)w;
  _Float16* Xl   = (_Float16*)(w + 2097152);
  _Float16* Rh   = (_Float16*)(w + 2097152);
  _Float16* Rl   = (_Float16*)(w + 2326528);
  float*    tneg = w + 2555904;
  float*    swg  = w + 2563072;
  _Float16* Qh   = (_Float16*)(w + 4194304);
  _Float16* Ql   = (_Float16*)(w + 6291456);
  float*    V    = w + 4194304;
  _Float16* Wqth = (_Float16*)(w + 8388608);
  _Float16* Wqtl = (_Float16*)(w + 8912896);
  float*    Ut   = w + 8388608;
  float*    ctxb = w;

  split_x<<<dim3(2048), dim3(256), 0, stream>>>(hs, Xh, Xl);
  transpose_split<<<dim3(16, 16), dim3(256), 0, stream>>>(Wq, Wqth, Wqtl);
  gemmq_mfma<<<dim3(16, 32), dim3(256), 0, stream>>>(Xh, Xl, Wqth, Wqtl, bq, Qh, Ql);
  prep_kernel<<<dim3(NP), dim3(64), 0, stream>>>(mu, prec, spw, Rh, Rl, tneg, swg);
  phi3<<<dim3(256, 8), dim3(256), 0, stream>>>(Qh, Ql, Rh, Rl, tneg, swg, Ut);
  gemm128<1><<<dim3(16, 32), dim3(256), 0, stream>>>(hs, Wv, bv, V);
  attn_kernel<<<dim3(4096), dim3(512), 0, stream>>>(Ut, V, amask, ctxb);
  gemm128<2><<<dim3(16, 32), dim3(256), 0, stream>>>(ctxb, Wo, bo, out);
}